// Round 5
// baseline (233.666 us; speedup 1.0000x reference)
//
#include <hip/hip_runtime.h>
#include <hip/hip_bf16.h>

typedef unsigned int u32;
typedef unsigned short u16;
typedef unsigned char u8;

typedef float f32x16 __attribute__((ext_vector_type(16)));
typedef short bf16x8 __attribute__((ext_vector_type(8)));

// ---- workspace layout (bytes after 64B header) -----------------------------
// A1eff[9 off][2 mt][2 hi][32 lane][8 k] bf16 (stencil folded into W1^T) 18432B
// A1b  [2 mt][2 hi][32 lane][8 k]       bf16 (b1/16 replicated)          2048B
// WT2p [32 ch][80 k]  bf16  K-PERMUTED to match o1 register order        5120B
// WT3p [32 row][32 k] bf16  K-permuted to o2 order, M-permuted so lane
//                           (n,hh) ends with ch 8hh..8hh+7 contiguous    2048B
// B3   [16] f32                                                            64B
#define OFF_A1  0
#define OFF_A1B 18432
#define OFF_WT2 20480
#define OFF_WT3 25600
#define OFF_B3  27648
#define PREP_N  13840   // 9216 + 1024 + 2560 + 1024 + 16

__device__ __forceinline__ float bf2f(u16 h) {
  return __uint_as_float(((u32)h) << 16);
}
__device__ __forceinline__ u16 f2bf(float f) {  // RNE (prep only)
  u32 u = __float_as_uint(f);
  return (u16)((u + 0x7FFFu + ((u >> 16) & 1u)) >> 16);
}
// hot-path pack: round-half-up + byte-perm (3 VALU ops)
__device__ __forceinline__ u32 pkbf(float a, float b) {
  u32 ua = __float_as_uint(a) + 0x8000u;
  u32 ub = __float_as_uint(b) + 0x8000u;
  return __builtin_amdgcn_perm(ub, ua, 0x07060302);  // {b.hi16, a.hi16}
}
__device__ __forceinline__ float rdv(const void* s, int i, bool bf) {
  return bf ? bf2f(((const u16*)s)[i]) : ((const float*)s)[i];
}

// ---------------------------------------------------------------------------
// Weight prep (probe folded in; verified R1-R4).
// K-permutation (layers 2,3): logical k-slot = 16s + 8hh + 2q + e must hold
// the channel resident in o{1,2}[4s+q] bf16-half e of a hh-half lane:
//   L2: c = 32*(s>>1) + 8*(2*(s&1)+(q>>1)) + 4*hh + 2*(q&1) + e
//   L3: c = 8*(2*s+(q>>1)) + 4*hh + 2*(q&1) + e
// M-permutation (layer 3): row r<16 holds output channel
//   cout(r) = (r&3) + 4*((r>>3)&1) + 8*((r>>2)&1)   (rows 16..31 zero)
// so lane (n,hh) reg e (e<8) = channel 8hh+e  -> contiguous 32B per lane.
// ---------------------------------------------------------------------------
__global__ void prep_weights(const void* __restrict__ w1, const void* __restrict__ b1,
                             const void* __restrict__ w2, const void* __restrict__ b2,
                             const void* __restrict__ w3, const void* __restrict__ b3,
                             u8* __restrict__ Wb) {
  __shared__ int sg;
  if (threadIdx.x == 0) sg = 0;
  __syncthreads();
  {
    const u16* w1h = (const u16*)w1;
    int g = 0;
#pragma unroll
    for (int k = 0; k < 8; ++k) {
      u16 h = w1h[threadIdx.x * 8 + k];
      int e = (h >> 7) & 0xFF;
      if (e >= 0xC0) g++;
    }
    if (g) atomicAdd(&sg, g);
  }
  __syncthreads();
  const bool bf = (sg == 0);

  int i = blockIdx.x * 256 + threadIdx.x;
  if (i >= PREP_N) return;
  if (i < 9216) {                       // A1eff
    int off = i >> 10, rem = i & 1023;
    int mt = rem >> 9, hi = (rem >> 8) & 1, l = (rem >> 3) & 31, k8 = i & 7;
    int ch = mt * 32 + l, k = hi * 8 + k8;
    int oi = off / 3, oj = off % 3;
    const float axv[3] = {1.f, 2.f, 1.f};
    const float bxv[3] = {-1.f, 0.f, 1.f};
    float ci  = (oi == 1 && oj == 1) ? 1.f : 0.f;
    float dxv = axv[oi] * bxv[oj] * 0.125f;
    float dyv = axv[oj] * bxv[oi] * 0.125f;
    float v = ci  * rdv(w1, (3 * k + 0) * 64 + ch, bf)
            + dxv * rdv(w1, (3 * k + 1) * 64 + ch, bf)
            + dyv * rdv(w1, (3 * k + 2) * 64 + ch, bf);
    ((u16*)(Wb + OFF_A1))[i] = f2bf(v);
  } else if (i < 10240) {               // A1b: b1/16 in every k slot
    int j = i - 9216;
    int mt = j >> 9, l = (j >> 3) & 31;
    ((u16*)(Wb + OFF_A1B))[j] = f2bf(rdv(b1, mt * 32 + l, bf) * 0.0625f);
  } else if (i < 12800) {               // WT2p (K-permuted)
    int j = i - 10240, n = j / 80, k = j - n * 80;
    float v;
    if (k < 64) {
      int s = k >> 4, hh = (k >> 3) & 1, q = (k & 7) >> 1, e = k & 1;
      int c = 32 * (s >> 1) + 8 * (2 * (s & 1) + (q >> 1)) + 4 * hh + 2 * (q & 1) + e;
      v = rdv(w2, c * 32 + n, bf);
    } else {
      v = (k == 64) ? rdv(b2, n, bf) : 0.0f;
    }
    ((u16*)(Wb + OFF_WT2))[j] = f2bf(v);
  } else if (i < 13824) {               // WT3p (K- and M-permuted)
    int j = i - 12800, n = j >> 5, k = j & 31;
    float v = 0.0f;
    if (n < 16) {
      int cout = (n & 3) + 4 * ((n >> 3) & 1) + 8 * ((n >> 2) & 1);
      int s = k >> 4, hh = (k >> 3) & 1, q = (k & 7) >> 1, e = k & 1;
      int cin = 8 * (2 * s + (q >> 1)) + 4 * hh + 2 * (q & 1) + e;
      v = rdv(w3, cin * 16 + cout, bf);
    }
    ((u16*)(Wb + OFF_WT3))[j] = f2bf(v);
  } else {                              // B3 f32
    int j = i - 13824;
    ((float*)(Wb + OFF_B3))[j] = rdv(b3, j, bf);
  }
}

// ---------------------------------------------------------------------------
// Main kernel
// ---------------------------------------------------------------------------
__device__ __forceinline__ float fast_tanh(float x) {
  float e = __expf(2.0f * x);
  float r = __builtin_amdgcn_rcpf(e + 1.0f);
  return fmaf(-2.0f, r, 1.0f);
}

union U4 { uint4 q; u32 u[4]; bf16x8 h; float4 f; };

#define MFMA(a, b, c) __builtin_amdgcn_mfma_f32_32x32x16_bf16((a), (b), (c), 0, 0, 0)

// LDS: xs[4 rows][258 cols][16 ch bf16] only (stride 8256B, halo cols 0/257
// zero). The dx transpose (px,ch)-per-lane -> chunk-per-lane is done with
// ds_bpermute ACROSS LANES (no LDS memory, no fences): dst lane l takes
// chunk (px=l>>2, c=l&3) of the 32-px tile from src lane
// s = (l>>2) + 32*((l>>1)&1), regs 4*(l&1)+j. Store addr = gpx0*16 + 4*l
// -> each store instruction covers a contiguous 1KB span = full 128B lines
// (R0's traffic shape: no RFO, x re-read stays L2-hot), while LDS drops
// 53504 -> 33024 and regs target R1's 64+64=128 -> 4 blocks/CU.
#define XS_STRIDE 8256
#define LDS_TOTAL 33024

template <bool BF16>
__device__ __forceinline__ void nca_body(const void* __restrict__ xv,
                                         const u8* __restrict__ Wb,
                                         const void* __restrict__ maskv, int mw,
                                         void* __restrict__ outv,
                                         u8* __restrict__ xs) {
  const int tid = threadIdx.x;
  const int l   = tid & 63;
  const int wid = tid >> 6;
  const int l31 = l & 31;
  const int hi  = l >> 5;
  const int img   = blockIdx.x >> 7;
  const int r0    = (blockIdx.x & 127) << 1;      // first of 2 output rows

  // ---- stage x rows r0-1 .. r0+2 into LDS as bf16 (zero halo) -------------
  if (tid < 8) {        // halo cols 0 and 257, 4 rows
    int rr = tid >> 1, side = tid & 1;
    uint4 z = make_uint4(0, 0, 0, 0);
    uint4* d = (uint4*)(xs + rr * XS_STRIDE + (side ? 257 : 0) * 32);
    d[0] = z; d[1] = z;
  }
#pragma unroll
  for (int rr = 0; rr < 4; ++rr) {
    int hr = r0 - 1 + rr;
    bool valid = (hr >= 0) && (hr <= 255);
    if (BF16) {
      const u16* src = (const u16*)xv + ((size_t)(img * 256 + hr) << 12);
#pragma unroll
      for (int s = 0; s < 2; ++s) {
        int c = s * 256 + tid;        // 16B chunk: col c>>1, half c&1
        uint4 v = make_uint4(0, 0, 0, 0);
        if (valid) v = *(const uint4*)(src + c * 8);
        *(uint4*)(xs + rr * XS_STRIDE + ((c >> 1) + 1) * 32 + (c & 1) * 16) = v;
      }
    } else {
      const float* src = (const float*)xv + ((size_t)(img * 256 + hr) << 12);
#pragma unroll
      for (int k = 0; k < 4; ++k) {
        int q = k * 256 + tid;        // float4 #q: col q>>2, ch-quad q&3
        uint2 w = make_uint2(0, 0);
        if (valid) {
          float4 v = *(const float4*)(src + q * 4);
          w.x = pkbf(v.x, v.y); w.y = pkbf(v.z, v.w);
        }
        *(uint2*)(xs + rr * XS_STRIDE + ((q >> 2) + 1) * 32 + (q & 3) * 8) = w;
      }
    }
  }
  __syncthreads();
  // After this point there are NO barriers and NO LDS writes: waves are
  // fully independent; cross-lane transpose uses ds_bpermute only.

  const int sr      = wid >> 1;                 // wave's top staged row
  const int colbase = (wid & 1) * 128;          // wave's column half
  const int gr      = img * 256 + r0 + sr;      // global image row
  const int growpix = gr << 8;                  // pixel index of row start

  // ---- hoisted invariants -------------------------------------------------
  bf16x8 A1b[2];
#pragma unroll
  for (int mt = 0; mt < 2; ++mt) {
    U4 t; t.q = *(const uint4*)(Wb + OFF_A1B + ((mt * 2 + hi) * 32 + l31) * 16);
    A1b[mt] = t.h;
  }
  U4 ones; ones.u[0] = ones.u[1] = ones.u[2] = ones.u[3] = 0x3F803F80u;
  const float* B3f = (const float*)(Wb + OFF_B3);
  float4 b3lo  = *(const float4*)(B3f + 8 * hi);      // ch 8hi+0..3
  float4 b3hi4 = *(const float4*)(B3f + 8 * hi + 4);  // ch 8hi+4..7
  // bpermute gather lane (bytes): src lane for chunk (px=l>>2, c=l&3)
  const int sidx = (((l >> 2) + ((l >> 1) & 1) * 32) << 2);

  // ---- 4 tiles of 32 px each ----------------------------------------------
#pragma unroll
  for (int t = 0; t < 4; ++t) {
    const int cb = colbase + t * 32;
    const int gpx0 = growpix + cb;            // first pixel of this tile

    // ---- layer 1: 2 bias MFMA + 9 shifted-offset MFMAs per M-tile ---------
    f32x16 c0 = {0,0,0,0,0,0,0,0,0,0,0,0,0,0,0,0};
    f32x16 c1 = {0,0,0,0,0,0,0,0,0,0,0,0,0,0,0,0};
    c0 = MFMA(A1b[0], ones.h, c0);
    c1 = MFMA(A1b[1], ones.h, c1);
#pragma unroll
    for (int off = 0; off < 9; ++off) {
      const int oi = off / 3, oj = off % 3;
      U4 bx; bx.q = *(const uint4*)(xs + (sr + oi) * XS_STRIDE +
                                    (cb + l31 + oj) * 32 + hi * 16);
      U4 a0; a0.q = *(const uint4*)(Wb + OFF_A1 + (((off * 2 + 0) * 2 + hi) * 32 + l31) * 16);
      U4 a1; a1.q = *(const uint4*)(Wb + OFF_A1 + (((off * 2 + 1) * 2 + hi) * 32 + l31) * 16);
      c0 = MFMA(a0.h, bx.h, c0);
      c1 = MFMA(a1.h, bx.h, c1);
    }

    // tanh + pack: o1[mt*8+g*2+pp] = ch(32mt+8g+4hi+2pp, +1)
    u32 o1[16];
#pragma unroll
    for (int g = 0; g < 4; ++g)
#pragma unroll
      for (int pp = 0; pp < 2; ++pp) {
        o1[g * 2 + pp]     = pkbf(fast_tanh(c0[g * 4 + 2 * pp]), fast_tanh(c0[g * 4 + 2 * pp + 1]));
        o1[8 + g * 2 + pp] = pkbf(fast_tanh(c1[g * 4 + 2 * pp]), fast_tanh(c1[g * 4 + 2 * pp + 1]));
      }

    // ---- layer 2: B-frag = o1[4s..4s+3] (K-permuted weights) --------------
    f32x16 c2 = {0,0,0,0,0,0,0,0,0,0,0,0,0,0,0,0};
#pragma unroll
    for (int s = 0; s < 4; ++s) {
      U4 a2; a2.q = *(const uint4*)(Wb + OFF_WT2 + l31 * 160 + s * 32 + hi * 16);
      U4 bfr; bfr.u[0] = o1[4*s]; bfr.u[1] = o1[4*s+1]; bfr.u[2] = o1[4*s+2]; bfr.u[3] = o1[4*s+3];
      c2 = MFMA(a2.h, bfr.h, c2);
    }
    {
      U4 a2; a2.q = *(const uint4*)(Wb + OFF_WT2 + l31 * 160 + 4 * 32 + hi * 16);
      U4 bb; bb.u[0] = hi ? 0u : 0x00003F80u; bb.u[1] = 0; bb.u[2] = 0; bb.u[3] = 0;
      c2 = MFMA(a2.h, bb.h, c2);
    }
    u32 o2[8];
#pragma unroll
    for (int g = 0; g < 4; ++g)
#pragma unroll
      for (int pp = 0; pp < 2; ++pp)
        o2[g * 2 + pp] = pkbf(fast_tanh(c2[g * 4 + 2 * pp]), fast_tanh(c2[g * 4 + 2 * pp + 1]));

    // ---- layer 3: B-frag = o2[4s..4s+3]; M-permuted -> lane has ch 8hi+e --
    f32x16 c3 = {0,0,0,0,0,0,0,0,0,0,0,0,0,0,0,0};
#pragma unroll
    for (int s = 0; s < 2; ++s) {
      U4 a3; a3.q = *(const uint4*)(Wb + OFF_WT3 + l31 * 64 + s * 32 + hi * 16);
      U4 bfr; bfr.u[0] = o2[4*s]; bfr.u[1] = o2[4*s+1]; bfr.u[2] = o2[4*s+2]; bfr.u[3] = o2[4*s+3];
      c3 = MFMA(a3.h, bfr.h, c3);
    }

    // ---- dx + b3 (lane = px cb+l31, ch 8hi..8hi+7) ------------------------
    float dd[8];
    dd[0] = c3[0] + b3lo.x;  dd[1] = c3[1] + b3lo.y;
    dd[2] = c3[2] + b3lo.z;  dd[3] = c3[3] + b3lo.w;
    dd[4] = c3[4] + b3hi4.x; dd[5] = c3[5] + b3hi4.y;
    dd[6] = c3[6] + b3hi4.z; dd[7] = c3[7] + b3hi4.w;

    // ---- epilogue: issue coalesced mask + x loads (L2-hot) ----------------
    const int p1 = gpx0 + (l >> 2);           // store1 pixel, lanes 4-aligned
    const int p2 = p1 + 16;                   // store2 pixel
    bool ms1, ms2;
    if (mw == 1)      { ms1 = ((const u8*)maskv)[p1] != 0;  ms2 = ((const u8*)maskv)[p2] != 0; }
    else if (mw == 2) { ms1 = ((const u16*)maskv)[p1] != 0; ms2 = ((const u16*)maskv)[p2] != 0; }
    else              { ms1 = ((const u32*)maskv)[p1] != 0; ms2 = ((const u32*)maskv)[p2] != 0; }
    const float mf1 = ms1 ? 1.0f : 0.0f;
    const float mf2 = ms2 ? 1.0f : 0.0f;
    const int e1 = gpx0 * 16 + 4 * l;         // element idx; wave covers 1KB
    const int e2 = e1 + 256;                  // contiguous per instruction

    // ---- cross-lane transpose: 16 bpermute + 8 cndmask --------------------
    u32 s1c[4], s2c[4];
#pragma unroll
    for (int j = 0; j < 4; ++j) {
      u32 va1 = (u32)__builtin_amdgcn_ds_bpermute(sidx,      __float_as_int(dd[j]));
      u32 vb1 = (u32)__builtin_amdgcn_ds_bpermute(sidx,      __float_as_int(dd[4 + j]));
      u32 va2 = (u32)__builtin_amdgcn_ds_bpermute(sidx + 64, __float_as_int(dd[j]));
      u32 vb2 = (u32)__builtin_amdgcn_ds_bpermute(sidx + 64, __float_as_int(dd[4 + j]));
      s1c[j] = (l & 1) ? vb1 : va1;
      s2c[j] = (l & 1) ? vb2 : va2;
    }

    if (BF16) {
      uint2 xu1 = *(const uint2*)((const u16*)xv + e1);
      uint2 xu2 = *(const uint2*)((const u16*)xv + e2);
      float x10 = bf2f((u16)(xu1.x & 0xFFFF)), x11 = bf2f((u16)(xu1.x >> 16));
      float x12 = bf2f((u16)(xu1.y & 0xFFFF)), x13 = bf2f((u16)(xu1.y >> 16));
      float x20 = bf2f((u16)(xu2.x & 0xFFFF)), x21 = bf2f((u16)(xu2.x >> 16));
      float x22 = bf2f((u16)(xu2.y & 0xFFFF)), x23 = bf2f((u16)(xu2.y >> 16));
      uint2 w1v, w2v;
      w1v.x = pkbf(fmaf(__uint_as_float(s1c[0]), mf1, x10),
                   fmaf(__uint_as_float(s1c[1]), mf1, x11));
      w1v.y = pkbf(fmaf(__uint_as_float(s1c[2]), mf1, x12),
                   fmaf(__uint_as_float(s1c[3]), mf1, x13));
      w2v.x = pkbf(fmaf(__uint_as_float(s2c[0]), mf2, x20),
                   fmaf(__uint_as_float(s2c[1]), mf2, x21));
      w2v.y = pkbf(fmaf(__uint_as_float(s2c[2]), mf2, x22),
                   fmaf(__uint_as_float(s2c[3]), mf2, x23));
      *(uint2*)((u16*)outv + e1) = w1v;
      *(uint2*)((u16*)outv + e2) = w2v;
    } else {
      float4 xc1 = *(const float4*)((const float*)xv + e1);
      float4 xc2 = *(const float4*)((const float*)xv + e2);
      float4 o1v, o2v;
      o1v.x = fmaf(__uint_as_float(s1c[0]), mf1, xc1.x);
      o1v.y = fmaf(__uint_as_float(s1c[1]), mf1, xc1.y);
      o1v.z = fmaf(__uint_as_float(s1c[2]), mf1, xc1.z);
      o1v.w = fmaf(__uint_as_float(s1c[3]), mf1, xc1.w);
      o2v.x = fmaf(__uint_as_float(s2c[0]), mf2, xc2.x);
      o2v.y = fmaf(__uint_as_float(s2c[1]), mf2, xc2.y);
      o2v.z = fmaf(__uint_as_float(s2c[2]), mf2, xc2.z);
      o2v.w = fmaf(__uint_as_float(s2c[3]), mf2, xc2.w);
      *(float4*)((float*)outv + e1) = o1v;
      *(float4*)((float*)outv + e2) = o2v;
    }
  }
}

__global__ __launch_bounds__(256, 4) void nca_main(const void* __restrict__ xv,
                                                   const u16* __restrict__ w1h,
                                                   const u8* __restrict__ Wb,
                                                   const void* __restrict__ maskv,
                                                   void* __restrict__ outv) {
  __shared__ __align__(16) u8 smem[LDS_TOTAL];
  __shared__ int sg, su8, sbf;
  if (threadIdx.x == 0) { sg = 0; su8 = 0; sbf = 0; }
  __syncthreads();
  {  // in-block probe (verified R1-R4; L2-hot reads, ~no cost)
    int g = 0;
#pragma unroll
    for (int k = 0; k < 8; ++k) {
      u16 h = w1h[threadIdx.x * 8 + k];
      int e = (h >> 7) & 0xFF;
      if (e >= 0xC0) g++;
    }
    if (g) atomicAdd(&sg, g);
    u32 w = ((const u32*)maskv)[threadIdx.x];
    bool bytes01 = ((w & 0xFEFEFEFEu) == 0u);
    int bsum = (int)(w & 1u) + (int)((w >> 8) & 1u) +
               (int)((w >> 16) & 1u) + (int)((w >> 24) & 1u);
    if (bytes01 && bsum >= 2) atomicAdd(&su8, 1);
    if (w == 0x3F803F80u || w == 0x00003F80u) atomicAdd(&sbf, 1);
  }
  __syncthreads();
  const bool isbf = (sg == 0);                  // wave-uniform
  const int mw = (su8 > 0) ? 1 : ((sbf > 0) ? 2 : 4);

  // NO XCD swizzle (neutral-at-best per R1/R3 traffic accounting).
  if (isbf) nca_body<true>(xv, Wb, maskv, mw, outv, smem);
  else      nca_body<false>(xv, Wb, maskv, mw, outv, smem);
}

// ---------------------------------------------------------------------------
extern "C" void kernel_launch(void* const* d_in, const int* in_sizes, int n_in,
                              void* d_out, int out_size, void* d_ws, size_t ws_size,
                              hipStream_t stream) {
  // d_in: 0=x, 1=w1, 2=b1, 3=w2, 4=b2, 5=w3, 6=b3, 7=update_mask
  u8* Wb = (u8*)d_ws + 64;

  prep_weights<<<(PREP_N + 255) / 256, 256, 0, stream>>>(
      d_in[1], d_in[2], d_in[3], d_in[4], d_in[5], d_in[6], Wb);

  const int pixels = in_sizes[7];            // B*H*W = 1048576
  const int blocks = pixels / 512;           // 2048: two 256-px rows per block
  nca_main<<<blocks, 256, 0, stream>>>(d_in[0], (const u16*)d_in[1], Wb,
                                       d_in[7], d_out);
}

// Round 6
// 190.704 us; speedup vs baseline: 1.2253x; 1.2253x over previous
//
#include <hip/hip_runtime.h>
#include <hip/hip_bf16.h>

typedef unsigned int u32;
typedef unsigned short u16;
typedef unsigned char u8;

typedef float f32x16 __attribute__((ext_vector_type(16)));
typedef short bf16x8 __attribute__((ext_vector_type(8)));

// ---- workspace layout (bytes after 64B header) -----------------------------
// A1eff[9 off][2 mt][2 hi][32 lane][8 k] bf16 (stencil folded into W1^T) 18432B
// A1b  [2 mt][2 hi][32 lane][8 k]       bf16 (b1/16 replicated)          2048B
// WT2p [32 ch][80 k]  bf16  K-PERMUTED to match o1 register order        5120B
// WT3p [32 row][32 k] bf16  K-permuted to o2 order, M-permuted so lane
//                           (n,hh) ends with ch 8hh..8hh+7 contiguous    2048B
// B3   [16] f32                                                            64B
#define OFF_A1  0
#define OFF_A1B 18432
#define OFF_WT2 20480
#define OFF_WT3 25600
#define OFF_B3  27648
#define PREP_N  13840   // 9216 + 1024 + 2560 + 1024 + 16

__device__ __forceinline__ float bf2f(u16 h) {
  return __uint_as_float(((u32)h) << 16);
}
__device__ __forceinline__ u16 f2bf(float f) {  // RNE (prep only)
  u32 u = __float_as_uint(f);
  return (u16)((u + 0x7FFFu + ((u >> 16) & 1u)) >> 16);
}
// hot-path pack: round-half-up + byte-perm (3 VALU ops)
__device__ __forceinline__ u32 pkbf(float a, float b) {
  u32 ua = __float_as_uint(a) + 0x8000u;
  u32 ub = __float_as_uint(b) + 0x8000u;
  return __builtin_amdgcn_perm(ub, ua, 0x07060302);  // {b.hi16, a.hi16}
}
__device__ __forceinline__ float rdv(const void* s, int i, bool bf) {
  return bf ? bf2f(((const u16*)s)[i]) : ((const float*)s)[i];
}

// ---------------------------------------------------------------------------
// Weight prep (probe folded in; verified R1-R5).
// K-permutation (layers 2,3): logical k-slot = 16s + 8hh + 2q + e must hold
// the channel resident in o{1,2}[4s+q] bf16-half e of a hh-half lane:
//   L2: c = 32*(s>>1) + 8*(2*(s&1)+(q>>1)) + 4*hh + 2*(q&1) + e
//   L3: c = 8*(2*s+(q>>1)) + 4*hh + 2*(q&1) + e
// M-permutation (layer 3): row r<16 holds output channel
//   cout(r) = (r&3) + 4*((r>>3)&1) + 8*((r>>2)&1)   (rows 16..31 zero)
// so lane (n,hh) reg e (e<8) = channel 8hh+e  -> contiguous 32B per lane.
// ---------------------------------------------------------------------------
__global__ void prep_weights(const void* __restrict__ w1, const void* __restrict__ b1,
                             const void* __restrict__ w2, const void* __restrict__ b2,
                             const void* __restrict__ w3, const void* __restrict__ b3,
                             u8* __restrict__ Wb) {
  __shared__ int sg;
  if (threadIdx.x == 0) sg = 0;
  __syncthreads();
  {
    const u16* w1h = (const u16*)w1;
    int g = 0;
#pragma unroll
    for (int k = 0; k < 8; ++k) {
      u16 h = w1h[threadIdx.x * 8 + k];
      int e = (h >> 7) & 0xFF;
      if (e >= 0xC0) g++;
    }
    if (g) atomicAdd(&sg, g);
  }
  __syncthreads();
  const bool bf = (sg == 0);

  int i = blockIdx.x * 256 + threadIdx.x;
  if (i >= PREP_N) return;
  if (i < 9216) {                       // A1eff
    int off = i >> 10, rem = i & 1023;
    int mt = rem >> 9, hi = (rem >> 8) & 1, l = (rem >> 3) & 31, k8 = i & 7;
    int ch = mt * 32 + l, k = hi * 8 + k8;
    int oi = off / 3, oj = off % 3;
    const float axv[3] = {1.f, 2.f, 1.f};
    const float bxv[3] = {-1.f, 0.f, 1.f};
    float ci  = (oi == 1 && oj == 1) ? 1.f : 0.f;
    float dxv = axv[oi] * bxv[oj] * 0.125f;
    float dyv = axv[oj] * bxv[oi] * 0.125f;
    float v = ci  * rdv(w1, (3 * k + 0) * 64 + ch, bf)
            + dxv * rdv(w1, (3 * k + 1) * 64 + ch, bf)
            + dyv * rdv(w1, (3 * k + 2) * 64 + ch, bf);
    ((u16*)(Wb + OFF_A1))[i] = f2bf(v);
  } else if (i < 10240) {               // A1b: b1/16 in every k slot
    int j = i - 9216;
    int mt = j >> 9, l = (j >> 3) & 31;
    ((u16*)(Wb + OFF_A1B))[j] = f2bf(rdv(b1, mt * 32 + l, bf) * 0.0625f);
  } else if (i < 12800) {               // WT2p (K-permuted)
    int j = i - 10240, n = j / 80, k = j - n * 80;
    float v;
    if (k < 64) {
      int s = k >> 4, hh = (k >> 3) & 1, q = (k & 7) >> 1, e = k & 1;
      int c = 32 * (s >> 1) + 8 * (2 * (s & 1) + (q >> 1)) + 4 * hh + 2 * (q & 1) + e;
      v = rdv(w2, c * 32 + n, bf);
    } else {
      v = (k == 64) ? rdv(b2, n, bf) : 0.0f;
    }
    ((u16*)(Wb + OFF_WT2))[j] = f2bf(v);
  } else if (i < 13824) {               // WT3p (K- and M-permuted)
    int j = i - 12800, n = j >> 5, k = j & 31;
    float v = 0.0f;
    if (n < 16) {
      int cout = (n & 3) + 4 * ((n >> 3) & 1) + 8 * ((n >> 2) & 1);
      int s = k >> 4, hh = (k >> 3) & 1, q = (k & 7) >> 1, e = k & 1;
      int cin = 8 * (2 * s + (q >> 1)) + 4 * hh + 2 * (q & 1) + e;
      v = rdv(w3, cin * 16 + cout, bf);
    }
    ((u16*)(Wb + OFF_WT3))[j] = f2bf(v);
  } else {                              // B3 f32
    int j = i - 13824;
    ((float*)(Wb + OFF_B3))[j] = rdv(b3, j, bf);
  }
}

// ---------------------------------------------------------------------------
// Main kernel
// ---------------------------------------------------------------------------
__device__ __forceinline__ float fast_tanh(float x) {
  float e = __expf(2.0f * x);
  float r = __builtin_amdgcn_rcpf(e + 1.0f);
  return fmaf(-2.0f, r, 1.0f);
}

union U4 { uint4 q; u32 u[4]; bf16x8 h; float4 f; };

__device__ __forceinline__ void wave_lds_fence() {
  __builtin_amdgcn_wave_barrier();
  __asm__ __volatile__("s_waitcnt lgkmcnt(0)" ::: "memory");
  __builtin_amdgcn_wave_barrier();
}

#define MFMA(a, b, c) __builtin_amdgcn_mfma_f32_32x32x16_bf16((a), (b), (c), 0, 0, 0)

// LDS: xs[4 rows][258 cols][16 ch bf16] (stride 8256B, halo cols 0/257 zero)
//    + scratch[4 waves][32 px][80B]  (PER-TILE now, was per-pair).
// R1/R3/R5 LAW: 4 blk/CU always loses ~+100-150MB of L2 hits (per-XCD L2
// can't hold 128 staged blocks) — but R0/R4's 53.5KB LDS only fit TWO blocks
// (3x53760 + runtime reserve > 160KB; measured occ 28% = 2.2 blk). Shrinking
// scratch to per-tile (2560B/wave) -> LDS 43264 -> a true 3 blk/CU with the
// traffic-clean scratch epilogue (full-line stores, no RFO, L2-hot re-read).
#define XS_STRIDE 8256
#define SCR_OFF   33024
#define SCR_WAVE  2560
#define LDS_TOTAL 43264

template <bool BF16>
__device__ __forceinline__ void nca_body(const void* __restrict__ xv,
                                         const u8* __restrict__ Wb,
                                         const void* __restrict__ maskv, int mw,
                                         void* __restrict__ outv,
                                         u8* __restrict__ xs) {
  const int tid = threadIdx.x;
  const int l   = tid & 63;
  const int wid = tid >> 6;
  const int l31 = l & 31;
  const int hi  = l >> 5;
  const int img   = blockIdx.x >> 7;
  const int r0    = (blockIdx.x & 127) << 1;      // first of 2 output rows

  // ---- stage x rows r0-1 .. r0+2 into LDS as bf16 (zero halo) -------------
  if (tid < 8) {        // halo cols 0 and 257, 4 rows
    int rr = tid >> 1, side = tid & 1;
    uint4 z = make_uint4(0, 0, 0, 0);
    uint4* d = (uint4*)(xs + rr * XS_STRIDE + (side ? 257 : 0) * 32);
    d[0] = z; d[1] = z;
  }
#pragma unroll
  for (int rr = 0; rr < 4; ++rr) {
    int hr = r0 - 1 + rr;
    bool valid = (hr >= 0) && (hr <= 255);
    if (BF16) {
      const u16* src = (const u16*)xv + ((size_t)(img * 256 + hr) << 12);
#pragma unroll
      for (int s = 0; s < 2; ++s) {
        int c = s * 256 + tid;        // 16B chunk: col c>>1, half c&1
        uint4 v = make_uint4(0, 0, 0, 0);
        if (valid) v = *(const uint4*)(src + c * 8);
        *(uint4*)(xs + rr * XS_STRIDE + ((c >> 1) + 1) * 32 + (c & 1) * 16) = v;
      }
    } else {
      const float* src = (const float*)xv + ((size_t)(img * 256 + hr) << 12);
#pragma unroll
      for (int k = 0; k < 4; ++k) {
        int q = k * 256 + tid;        // float4 #q: col q>>2, ch-quad q&3
        uint2 w = make_uint2(0, 0);
        if (valid) {
          float4 v = *(const float4*)(src + q * 4);
          w.x = pkbf(v.x, v.y); w.y = pkbf(v.z, v.w);
        }
        *(uint2*)(xs + rr * XS_STRIDE + ((q >> 2) + 1) * 32 + (q & 3) * 8) = w;
      }
    }
  }
  __syncthreads();

  const int sr      = wid >> 1;                 // wave's top staged row
  const int colbase = (wid & 1) * 128;          // wave's column half
  const int gr      = img * 256 + r0 + sr;      // global image row
  const int growpix = gr << 8;                  // pixel index of row start

  // ---- hoisted invariants -------------------------------------------------
  bf16x8 A1b[2];
#pragma unroll
  for (int mt = 0; mt < 2; ++mt) {
    U4 t; t.q = *(const uint4*)(Wb + OFF_A1B + ((mt * 2 + hi) * 32 + l31) * 16);
    A1b[mt] = t.h;
  }
  U4 ones; ones.u[0] = ones.u[1] = ones.u[2] = ones.u[3] = 0x3F803F80u;
  const float* B3f = (const float*)(Wb + OFF_B3);
  float4 b3lo = *(const float4*)(B3f + 8 * hi);       // ch 8hi+0..3
  float4 b3hi4 = *(const float4*)(B3f + 8 * hi + 4);  // ch 8hi+4..7
  u8* scr = xs + SCR_OFF + wid * SCR_WAVE;

  // ---- 4 tiles of 32 px each ----------------------------------------------
#pragma unroll
  for (int t = 0; t < 4; ++t) {
    const int cb = colbase + t * 32;

    // ---- layer 1: 2 bias MFMA + 9 shifted-offset MFMAs per M-tile ---------
    f32x16 c0 = {0,0,0,0,0,0,0,0,0,0,0,0,0,0,0,0};
    f32x16 c1 = {0,0,0,0,0,0,0,0,0,0,0,0,0,0,0,0};
    c0 = MFMA(A1b[0], ones.h, c0);
    c1 = MFMA(A1b[1], ones.h, c1);
#pragma unroll
    for (int off = 0; off < 9; ++off) {
      const int oi = off / 3, oj = off % 3;
      U4 bx; bx.q = *(const uint4*)(xs + (sr + oi) * XS_STRIDE +
                                    (cb + l31 + oj) * 32 + hi * 16);
      U4 a0; a0.q = *(const uint4*)(Wb + OFF_A1 + (((off * 2 + 0) * 2 + hi) * 32 + l31) * 16);
      U4 a1; a1.q = *(const uint4*)(Wb + OFF_A1 + (((off * 2 + 1) * 2 + hi) * 32 + l31) * 16);
      c0 = MFMA(a0.h, bx.h, c0);
      c1 = MFMA(a1.h, bx.h, c1);
    }

    // tanh + pack: o1[mt*8+g*2+pp] = ch(32mt+8g+4hi+2pp, +1)
    u32 o1[16];
#pragma unroll
    for (int g = 0; g < 4; ++g)
#pragma unroll
      for (int pp = 0; pp < 2; ++pp) {
        o1[g * 2 + pp]     = pkbf(fast_tanh(c0[g * 4 + 2 * pp]), fast_tanh(c0[g * 4 + 2 * pp + 1]));
        o1[8 + g * 2 + pp] = pkbf(fast_tanh(c1[g * 4 + 2 * pp]), fast_tanh(c1[g * 4 + 2 * pp + 1]));
      }

    // ---- layer 2: B-frag = o1[4s..4s+3] (K-permuted weights) --------------
    f32x16 c2 = {0,0,0,0,0,0,0,0,0,0,0,0,0,0,0,0};
#pragma unroll
    for (int s = 0; s < 4; ++s) {
      U4 a2; a2.q = *(const uint4*)(Wb + OFF_WT2 + l31 * 160 + s * 32 + hi * 16);
      U4 bfr; bfr.u[0] = o1[4*s]; bfr.u[1] = o1[4*s+1]; bfr.u[2] = o1[4*s+2]; bfr.u[3] = o1[4*s+3];
      c2 = MFMA(a2.h, bfr.h, c2);
    }
    {
      U4 a2; a2.q = *(const uint4*)(Wb + OFF_WT2 + l31 * 160 + 4 * 32 + hi * 16);
      U4 bb; bb.u[0] = hi ? 0u : 0x00003F80u; bb.u[1] = 0; bb.u[2] = 0; bb.u[3] = 0;
      c2 = MFMA(a2.h, bb.h, c2);
    }
    u32 o2[8];
#pragma unroll
    for (int g = 0; g < 4; ++g)
#pragma unroll
      for (int pp = 0; pp < 2; ++pp)
        o2[g * 2 + pp] = pkbf(fast_tanh(c2[g * 4 + 2 * pp]), fast_tanh(c2[g * 4 + 2 * pp + 1]));

    // ---- layer 3: B-frag = o2[4s..4s+3]; M-permuted -> lane has ch 8hi+e --
    f32x16 c3 = {0,0,0,0,0,0,0,0,0,0,0,0,0,0,0,0};
#pragma unroll
    for (int s = 0; s < 2; ++s) {
      U4 a3; a3.q = *(const uint4*)(Wb + OFF_WT3 + l31 * 64 + s * 32 + hi * 16);
      U4 bfr; bfr.u[0] = o2[4*s]; bfr.u[1] = o2[4*s+1]; bfr.u[2] = o2[4*s+2]; bfr.u[3] = o2[4*s+3];
      c3 = MFMA(a3.h, bfr.h, c3);
    }

    // dx + b3 -> per-wave LDS scratch (transpose for coalesced epilogue)
    U4 w0, w1;
    w0.f.x = c3[0] + b3lo.x;  w0.f.y = c3[1] + b3lo.y;
    w0.f.z = c3[2] + b3lo.z;  w0.f.w = c3[3] + b3lo.w;
    w1.f.x = c3[4] + b3hi4.x; w1.f.y = c3[5] + b3hi4.y;
    w1.f.z = c3[6] + b3hi4.z; w1.f.w = c3[7] + b3hi4.w;
    u8* sa = scr + l31 * 80 + hi * 32;
    *(float4*)(sa) = w0.f;
    *(float4*)(sa + 16) = w1.f;
    wave_lds_fence();

    // ---- epilogue for this tile's 32 px: coalesced x reads + out writes ---
#pragma unroll
    for (int P = 0; P < 2; ++P) {
      const int px_l = P * 16 + (l >> 2);       // 0..31
      const int qd   = l & 3;                   // channel quad
      float4 dx = *(const float4*)(scr + px_l * 80 + qd * 16);
      const int gpx = growpix + cb + px_l;
      bool ms;
      if (mw == 1)      ms = ((const u8*)maskv)[gpx] != 0;
      else if (mw == 2) ms = ((const u16*)maskv)[gpx] != 0;
      else              ms = ((const u32*)maskv)[gpx] != 0;
      const float mf = ms ? 1.0f : 0.0f;
      const int e = gpx * 16 + qd * 4;
      if (BF16) {
        uint2 xu = *(const uint2*)((const u16*)xv + e);
        float x0 = bf2f((u16)(xu.x & 0xFFFF)), x1 = bf2f((u16)(xu.x >> 16));
        float x2 = bf2f((u16)(xu.y & 0xFFFF)), x3 = bf2f((u16)(xu.y >> 16));
        float o0 = fmaf(dx.x, mf, x0), o1v = fmaf(dx.y, mf, x1);
        float o2v = fmaf(dx.z, mf, x2), o3v = fmaf(dx.w, mf, x3);
        uint2 w; w.x = pkbf(o0, o1v); w.y = pkbf(o2v, o3v);
        *(uint2*)((u16*)outv + e) = w;
      } else {
        float4 xc = *(const float4*)((const float*)xv + e);
        float4 o;
        o.x = fmaf(dx.x, mf, xc.x); o.y = fmaf(dx.y, mf, xc.y);
        o.z = fmaf(dx.z, mf, xc.z); o.w = fmaf(dx.w, mf, xc.w);
        *(float4*)((float*)outv + e) = o;
      }
    }
    wave_lds_fence();   // reads done before next tile's scratch writes
  }
}

__global__ __launch_bounds__(256, 3) void nca_main(const void* __restrict__ xv,
                                                   const u16* __restrict__ w1h,
                                                   const u8* __restrict__ Wb,
                                                   const void* __restrict__ maskv,
                                                   void* __restrict__ outv) {
  __shared__ __align__(16) u8 smem[LDS_TOTAL];
  __shared__ int sg, su8, sbf;
  if (threadIdx.x == 0) { sg = 0; su8 = 0; sbf = 0; }
  __syncthreads();
  {  // in-block probe (verified R1-R5; L2-hot reads, ~no cost)
    int g = 0;
#pragma unroll
    for (int k = 0; k < 8; ++k) {
      u16 h = w1h[threadIdx.x * 8 + k];
      int e = (h >> 7) & 0xFF;
      if (e >= 0xC0) g++;
    }
    if (g) atomicAdd(&sg, g);
    u32 w = ((const u32*)maskv)[threadIdx.x];
    bool bytes01 = ((w & 0xFEFEFEFEu) == 0u);
    int bsum = (int)(w & 1u) + (int)((w >> 8) & 1u) +
               (int)((w >> 16) & 1u) + (int)((w >> 24) & 1u);
    if (bytes01 && bsum >= 2) atomicAdd(&su8, 1);
    if (w == 0x3F803F80u || w == 0x00003F80u) atomicAdd(&sbf, 1);
  }
  __syncthreads();
  const bool isbf = (sg == 0);                  // wave-uniform
  const int mw = (su8 > 0) ? 1 : ((sbf > 0) ? 2 : 4);

  // NO XCD swizzle (neutral-at-best per R1/R3 traffic accounting).
  if (isbf) nca_body<true>(xv, Wb, maskv, mw, outv, smem);
  else      nca_body<false>(xv, Wb, maskv, mw, outv, smem);
}

// ---------------------------------------------------------------------------
extern "C" void kernel_launch(void* const* d_in, const int* in_sizes, int n_in,
                              void* d_out, int out_size, void* d_ws, size_t ws_size,
                              hipStream_t stream) {
  // d_in: 0=x, 1=w1, 2=b1, 3=w2, 4=b2, 5=w3, 6=b3, 7=update_mask
  u8* Wb = (u8*)d_ws + 64;

  prep_weights<<<(PREP_N + 255) / 256, 256, 0, stream>>>(
      d_in[1], d_in[2], d_in[3], d_in[4], d_in[5], d_in[6], Wb);

  const int pixels = in_sizes[7];            // B*H*W = 1048576
  const int blocks = pixels / 512;           // 2048: two 256-px rows per block
  nca_main<<<blocks, 256, 0, stream>>>(d_in[0], (const u16*)d_in[1], Wb,
                                       d_in[7], d_out);
}

// Round 7
// 189.381 us; speedup vs baseline: 1.2338x; 1.0070x over previous
//
#include <hip/hip_runtime.h>
#include <hip/hip_bf16.h>

typedef unsigned int u32;
typedef unsigned short u16;
typedef unsigned char u8;

typedef float f32x16 __attribute__((ext_vector_type(16)));
typedef short bf16x8 __attribute__((ext_vector_type(8)));

// ---- workspace layout (bytes after 64B header) -----------------------------
// A1eff[9 off][2 mt][2 hi][32 lane][8 k] bf16 (stencil folded into W1^T) 18432B
// A1b  [2 mt][2 hi][32 lane][8 k]       bf16 (b1/16 replicated)          2048B
// WT2p [32 ch][80 k]  bf16  K-PERMUTED to match o1 register order        5120B
// WT3p [32 row][32 k] bf16  K-permuted to o2 order, M-permuted so lane
//                           (n,hh) ends with ch 8hh..8hh+7 contiguous    2048B
// B3   [16] f32                                                            64B
#define OFF_A1  0
#define OFF_A1B 18432
#define OFF_WT2 20480
#define OFF_WT3 25600
#define OFF_B3  27648
#define PREP_N  13840   // 9216 + 1024 + 2560 + 1024 + 16

__device__ __forceinline__ float bf2f(u16 h) {
  return __uint_as_float(((u32)h) << 16);
}
__device__ __forceinline__ u16 f2bf(float f) {  // RNE (prep only)
  u32 u = __float_as_uint(f);
  return (u16)((u + 0x7FFFu + ((u >> 16) & 1u)) >> 16);
}
// hot-path pack: single v_cvt_pk_bf16_f32 (RNE), replaces 3-op add/add/perm.
// Non-volatile asm: pure value op, scheduler may move/CSE it.
__device__ __forceinline__ u32 pkbf(float a, float b) {
  u32 r;
  asm("v_cvt_pk_bf16_f32 %0, %1, %2" : "=v"(r) : "v"(a), "v"(b));
  return r;  // lo16 = bf16(a), hi16 = bf16(b) — same layout as old perm pack
}
__device__ __forceinline__ float rdv(const void* s, int i, bool bf) {
  return bf ? bf2f(((const u16*)s)[i]) : ((const float*)s)[i];
}

// ---------------------------------------------------------------------------
// Weight prep (probe folded in; verified R1-R6).
// K-permutation (layers 2,3): logical k-slot = 16s + 8hh + 2q + e must hold
// the channel resident in o{1,2}[4s+q] bf16-half e of a hh-half lane:
//   L2: c = 32*(s>>1) + 8*(2*(s&1)+(q>>1)) + 4*hh + 2*(q&1) + e
//   L3: c = 8*(2*s+(q>>1)) + 4*hh + 2*(q&1) + e
// M-permutation (layer 3): row r<16 holds output channel
//   cout(r) = (r&3) + 4*((r>>3)&1) + 8*((r>>2)&1)   (rows 16..31 zero)
// so lane (n,hh) reg e (e<8) = channel 8hh+e  -> contiguous 32B per lane.
// ---------------------------------------------------------------------------
__global__ void prep_weights(const void* __restrict__ w1, const void* __restrict__ b1,
                             const void* __restrict__ w2, const void* __restrict__ b2,
                             const void* __restrict__ w3, const void* __restrict__ b3,
                             u8* __restrict__ Wb) {
  __shared__ int sg;
  if (threadIdx.x == 0) sg = 0;
  __syncthreads();
  {
    const u16* w1h = (const u16*)w1;
    int g = 0;
#pragma unroll
    for (int k = 0; k < 8; ++k) {
      u16 h = w1h[threadIdx.x * 8 + k];
      int e = (h >> 7) & 0xFF;
      if (e >= 0xC0) g++;
    }
    if (g) atomicAdd(&sg, g);
  }
  __syncthreads();
  const bool bf = (sg == 0);

  int i = blockIdx.x * 256 + threadIdx.x;
  if (i >= PREP_N) return;
  if (i < 9216) {                       // A1eff
    int off = i >> 10, rem = i & 1023;
    int mt = rem >> 9, hi = (rem >> 8) & 1, l = (rem >> 3) & 31, k8 = i & 7;
    int ch = mt * 32 + l, k = hi * 8 + k8;
    int oi = off / 3, oj = off % 3;
    const float axv[3] = {1.f, 2.f, 1.f};
    const float bxv[3] = {-1.f, 0.f, 1.f};
    float ci  = (oi == 1 && oj == 1) ? 1.f : 0.f;
    float dxv = axv[oi] * bxv[oj] * 0.125f;
    float dyv = axv[oj] * bxv[oi] * 0.125f;
    float v = ci  * rdv(w1, (3 * k + 0) * 64 + ch, bf)
            + dxv * rdv(w1, (3 * k + 1) * 64 + ch, bf)
            + dyv * rdv(w1, (3 * k + 2) * 64 + ch, bf);
    ((u16*)(Wb + OFF_A1))[i] = f2bf(v);
  } else if (i < 10240) {               // A1b: b1/16 in every k slot
    int j = i - 9216;
    int mt = j >> 9, l = (j >> 3) & 31;
    ((u16*)(Wb + OFF_A1B))[j] = f2bf(rdv(b1, mt * 32 + l, bf) * 0.0625f);
  } else if (i < 12800) {               // WT2p (K-permuted)
    int j = i - 10240, n = j / 80, k = j - n * 80;
    float v;
    if (k < 64) {
      int s = k >> 4, hh = (k >> 3) & 1, q = (k & 7) >> 1, e = k & 1;
      int c = 32 * (s >> 1) + 8 * (2 * (s & 1) + (q >> 1)) + 4 * hh + 2 * (q & 1) + e;
      v = rdv(w2, c * 32 + n, bf);
    } else {
      v = (k == 64) ? rdv(b2, n, bf) : 0.0f;
    }
    ((u16*)(Wb + OFF_WT2))[j] = f2bf(v);
  } else if (i < 13824) {               // WT3p (K- and M-permuted)
    int j = i - 12800, n = j >> 5, k = j & 31;
    float v = 0.0f;
    if (n < 16) {
      int cout = (n & 3) + 4 * ((n >> 3) & 1) + 8 * ((n >> 2) & 1);
      int s = k >> 4, hh = (k >> 3) & 1, q = (k & 7) >> 1, e = k & 1;
      int cin = 8 * (2 * s + (q >> 1)) + 4 * hh + 2 * (q & 1) + e;
      v = rdv(w3, cin * 16 + cout, bf);
    }
    ((u16*)(Wb + OFF_WT3))[j] = f2bf(v);
  } else {                              // B3 f32
    int j = i - 13824;
    ((float*)(Wb + OFF_B3))[j] = rdv(b3, j, bf);
  }
}

// ---------------------------------------------------------------------------
// Main kernel
// ---------------------------------------------------------------------------
// tanh(x) = 1 - 2/(e^{2x}+1);  e^{2x} = 2^{x * 2/ln2}  (one mul + v_exp_f32)
__device__ __forceinline__ float fast_tanh(float x) {
  float e = __builtin_amdgcn_exp2f(x * 2.8853900817779268f);
  float r = __builtin_amdgcn_rcpf(e + 1.0f);
  return fmaf(-2.0f, r, 1.0f);
}

union U4 { uint4 q; u32 u[4]; bf16x8 h; float4 f; };

__device__ __forceinline__ void wave_lds_fence() {
  __builtin_amdgcn_wave_barrier();
  __asm__ __volatile__("s_waitcnt lgkmcnt(0)" ::: "memory");
  __builtin_amdgcn_wave_barrier();
}

#define MFMA(a, b, c) __builtin_amdgcn_mfma_f32_32x32x16_bf16((a), (b), (c), 0, 0, 0)

// LDS: xs[4 rows][258 cols][16 ch bf16] (stride 8256B, halo cols 0/257 zero)
//    + scratch[4 waves][32 px][80B]  (per-tile; verified R6).
// R6 verified: 43264B -> 3 blk/CU, FETCH 90MB (halo+epilogue L2-hot),
// WRITE 64MiB exact (full-line stores, no RFO). 4 blk/CU is traffic-poisoned
// (R1/R3/R5: +100-150MB FETCH) — occupancy lever closed; VALU is now the
// largest time component (34% of 95µs), attacked this round via
// v_cvt_pk_bf16_f32 (3->1 inst per pack) and exp2-folded tanh (6->5).
#define XS_STRIDE 8256
#define SCR_OFF   33024
#define SCR_WAVE  2560
#define LDS_TOTAL 43264

template <bool BF16>
__device__ __forceinline__ void nca_body(const void* __restrict__ xv,
                                         const u8* __restrict__ Wb,
                                         const void* __restrict__ maskv, int mw,
                                         void* __restrict__ outv,
                                         u8* __restrict__ xs) {
  const int tid = threadIdx.x;
  const int l   = tid & 63;
  const int wid = tid >> 6;
  const int l31 = l & 31;
  const int hi  = l >> 5;
  const int img   = blockIdx.x >> 7;
  const int r0    = (blockIdx.x & 127) << 1;      // first of 2 output rows

  // ---- stage x rows r0-1 .. r0+2 into LDS as bf16 (zero halo) -------------
  if (tid < 8) {        // halo cols 0 and 257, 4 rows
    int rr = tid >> 1, side = tid & 1;
    uint4 z = make_uint4(0, 0, 0, 0);
    uint4* d = (uint4*)(xs + rr * XS_STRIDE + (side ? 257 : 0) * 32);
    d[0] = z; d[1] = z;
  }
#pragma unroll
  for (int rr = 0; rr < 4; ++rr) {
    int hr = r0 - 1 + rr;
    bool valid = (hr >= 0) && (hr <= 255);
    if (BF16) {
      const u16* src = (const u16*)xv + ((size_t)(img * 256 + hr) << 12);
#pragma unroll
      for (int s = 0; s < 2; ++s) {
        int c = s * 256 + tid;        // 16B chunk: col c>>1, half c&1
        uint4 v = make_uint4(0, 0, 0, 0);
        if (valid) v = *(const uint4*)(src + c * 8);
        *(uint4*)(xs + rr * XS_STRIDE + ((c >> 1) + 1) * 32 + (c & 1) * 16) = v;
      }
    } else {
      const float* src = (const float*)xv + ((size_t)(img * 256 + hr) << 12);
#pragma unroll
      for (int k = 0; k < 4; ++k) {
        int q = k * 256 + tid;        // float4 #q: col q>>2, ch-quad q&3
        uint2 w = make_uint2(0, 0);
        if (valid) {
          float4 v = *(const float4*)(src + q * 4);
          w.x = pkbf(v.x, v.y); w.y = pkbf(v.z, v.w);
        }
        *(uint2*)(xs + rr * XS_STRIDE + ((q >> 2) + 1) * 32 + (q & 3) * 8) = w;
      }
    }
  }
  __syncthreads();

  const int sr      = wid >> 1;                 // wave's top staged row
  const int colbase = (wid & 1) * 128;          // wave's column half
  const int gr      = img * 256 + r0 + sr;      // global image row
  const int growpix = gr << 8;                  // pixel index of row start

  // ---- hoisted invariants -------------------------------------------------
  bf16x8 A1b[2];
#pragma unroll
  for (int mt = 0; mt < 2; ++mt) {
    U4 t; t.q = *(const uint4*)(Wb + OFF_A1B + ((mt * 2 + hi) * 32 + l31) * 16);
    A1b[mt] = t.h;
  }
  U4 ones; ones.u[0] = ones.u[1] = ones.u[2] = ones.u[3] = 0x3F803F80u;
  const float* B3f = (const float*)(Wb + OFF_B3);
  float4 b3lo = *(const float4*)(B3f + 8 * hi);       // ch 8hi+0..3
  float4 b3hi4 = *(const float4*)(B3f + 8 * hi + 4);  // ch 8hi+4..7
  u8* scr = xs + SCR_OFF + wid * SCR_WAVE;

  // ---- 4 tiles of 32 px each ----------------------------------------------
#pragma unroll
  for (int t = 0; t < 4; ++t) {
    const int cb = colbase + t * 32;

    // ---- layer 1: 2 bias MFMA + 9 shifted-offset MFMAs per M-tile ---------
    f32x16 c0 = {0,0,0,0,0,0,0,0,0,0,0,0,0,0,0,0};
    f32x16 c1 = {0,0,0,0,0,0,0,0,0,0,0,0,0,0,0,0};
    c0 = MFMA(A1b[0], ones.h, c0);
    c1 = MFMA(A1b[1], ones.h, c1);
#pragma unroll
    for (int off = 0; off < 9; ++off) {
      const int oi = off / 3, oj = off % 3;
      U4 bx; bx.q = *(const uint4*)(xs + (sr + oi) * XS_STRIDE +
                                    (cb + l31 + oj) * 32 + hi * 16);
      U4 a0; a0.q = *(const uint4*)(Wb + OFF_A1 + (((off * 2 + 0) * 2 + hi) * 32 + l31) * 16);
      U4 a1; a1.q = *(const uint4*)(Wb + OFF_A1 + (((off * 2 + 1) * 2 + hi) * 32 + l31) * 16);
      c0 = MFMA(a0.h, bx.h, c0);
      c1 = MFMA(a1.h, bx.h, c1);
    }

    // tanh + pack: o1[mt*8+g*2+pp] = ch(32mt+8g+4hi+2pp, +1)
    u32 o1[16];
#pragma unroll
    for (int g = 0; g < 4; ++g)
#pragma unroll
      for (int pp = 0; pp < 2; ++pp) {
        o1[g * 2 + pp]     = pkbf(fast_tanh(c0[g * 4 + 2 * pp]), fast_tanh(c0[g * 4 + 2 * pp + 1]));
        o1[8 + g * 2 + pp] = pkbf(fast_tanh(c1[g * 4 + 2 * pp]), fast_tanh(c1[g * 4 + 2 * pp + 1]));
      }

    // ---- layer 2: B-frag = o1[4s..4s+3] (K-permuted weights) --------------
    f32x16 c2 = {0,0,0,0,0,0,0,0,0,0,0,0,0,0,0,0};
#pragma unroll
    for (int s = 0; s < 4; ++s) {
      U4 a2; a2.q = *(const uint4*)(Wb + OFF_WT2 + l31 * 160 + s * 32 + hi * 16);
      U4 bfr; bfr.u[0] = o1[4*s]; bfr.u[1] = o1[4*s+1]; bfr.u[2] = o1[4*s+2]; bfr.u[3] = o1[4*s+3];
      c2 = MFMA(a2.h, bfr.h, c2);
    }
    {
      U4 a2; a2.q = *(const uint4*)(Wb + OFF_WT2 + l31 * 160 + 4 * 32 + hi * 16);
      U4 bb; bb.u[0] = hi ? 0u : 0x00003F80u; bb.u[1] = 0; bb.u[2] = 0; bb.u[3] = 0;
      c2 = MFMA(a2.h, bb.h, c2);
    }
    u32 o2[8];
#pragma unroll
    for (int g = 0; g < 4; ++g)
#pragma unroll
      for (int pp = 0; pp < 2; ++pp)
        o2[g * 2 + pp] = pkbf(fast_tanh(c2[g * 4 + 2 * pp]), fast_tanh(c2[g * 4 + 2 * pp + 1]));

    // ---- layer 3: B-frag = o2[4s..4s+3]; M-permuted -> lane has ch 8hi+e --
    f32x16 c3 = {0,0,0,0,0,0,0,0,0,0,0,0,0,0,0,0};
#pragma unroll
    for (int s = 0; s < 2; ++s) {
      U4 a3; a3.q = *(const uint4*)(Wb + OFF_WT3 + l31 * 64 + s * 32 + hi * 16);
      U4 bfr; bfr.u[0] = o2[4*s]; bfr.u[1] = o2[4*s+1]; bfr.u[2] = o2[4*s+2]; bfr.u[3] = o2[4*s+3];
      c3 = MFMA(a3.h, bfr.h, c3);
    }

    // dx + b3 -> per-wave LDS scratch (transpose for coalesced epilogue)
    U4 w0, w1;
    w0.f.x = c3[0] + b3lo.x;  w0.f.y = c3[1] + b3lo.y;
    w0.f.z = c3[2] + b3lo.z;  w0.f.w = c3[3] + b3lo.w;
    w1.f.x = c3[4] + b3hi4.x; w1.f.y = c3[5] + b3hi4.y;
    w1.f.z = c3[6] + b3hi4.z; w1.f.w = c3[7] + b3hi4.w;
    u8* sa = scr + l31 * 80 + hi * 32;
    *(float4*)(sa) = w0.f;
    *(float4*)(sa + 16) = w1.f;
    wave_lds_fence();

    // ---- epilogue for this tile's 32 px: coalesced x reads + out writes ---
#pragma unroll
    for (int P = 0; P < 2; ++P) {
      const int px_l = P * 16 + (l >> 2);       // 0..31
      const int qd   = l & 3;                   // channel quad
      float4 dx = *(const float4*)(scr + px_l * 80 + qd * 16);
      const int gpx = growpix + cb + px_l;
      bool ms;
      if (mw == 1)      ms = ((const u8*)maskv)[gpx] != 0;
      else if (mw == 2) ms = ((const u16*)maskv)[gpx] != 0;
      else              ms = ((const u32*)maskv)[gpx] != 0;
      const float mf = ms ? 1.0f : 0.0f;
      const int e = gpx * 16 + qd * 4;
      if (BF16) {
        uint2 xu = *(const uint2*)((const u16*)xv + e);
        float x0 = bf2f((u16)(xu.x & 0xFFFF)), x1 = bf2f((u16)(xu.x >> 16));
        float x2 = bf2f((u16)(xu.y & 0xFFFF)), x3 = bf2f((u16)(xu.y >> 16));
        float o0 = fmaf(dx.x, mf, x0), o1v = fmaf(dx.y, mf, x1);
        float o2v = fmaf(dx.z, mf, x2), o3v = fmaf(dx.w, mf, x3);
        uint2 w; w.x = pkbf(o0, o1v); w.y = pkbf(o2v, o3v);
        *(uint2*)((u16*)outv + e) = w;
      } else {
        float4 xc = *(const float4*)((const float*)xv + e);
        float4 o;
        o.x = fmaf(dx.x, mf, xc.x); o.y = fmaf(dx.y, mf, xc.y);
        o.z = fmaf(dx.z, mf, xc.z); o.w = fmaf(dx.w, mf, xc.w);
        *(float4*)((float*)outv + e) = o;
      }
    }
    wave_lds_fence();   // reads done before next tile's scratch writes
  }
}

__global__ __launch_bounds__(256, 3) void nca_main(const void* __restrict__ xv,
                                                   const u16* __restrict__ w1h,
                                                   const u8* __restrict__ Wb,
                                                   const void* __restrict__ maskv,
                                                   void* __restrict__ outv) {
  __shared__ __align__(16) u8 smem[LDS_TOTAL];
  __shared__ int sg, su8, sbf;
  if (threadIdx.x == 0) { sg = 0; su8 = 0; sbf = 0; }
  __syncthreads();
  {  // in-block probe (verified R1-R6; L2-hot reads, ~no cost)
    int g = 0;
#pragma unroll
    for (int k = 0; k < 8; ++k) {
      u16 h = w1h[threadIdx.x * 8 + k];
      int e = (h >> 7) & 0xFF;
      if (e >= 0xC0) g++;
    }
    if (g) atomicAdd(&sg, g);
    u32 w = ((const u32*)maskv)[threadIdx.x];
    bool bytes01 = ((w & 0xFEFEFEFEu) == 0u);
    int bsum = (int)(w & 1u) + (int)((w >> 8) & 1u) +
               (int)((w >> 16) & 1u) + (int)((w >> 24) & 1u);
    if (bytes01 && bsum >= 2) atomicAdd(&su8, 1);
    if (w == 0x3F803F80u || w == 0x00003F80u) atomicAdd(&sbf, 1);
  }
  __syncthreads();
  const bool isbf = (sg == 0);                  // wave-uniform
  const int mw = (su8 > 0) ? 1 : ((sbf > 0) ? 2 : 4);

  // NO XCD swizzle (neutral-at-best per R1/R3 traffic accounting).
  if (isbf) nca_body<true>(xv, Wb, maskv, mw, outv, smem);
  else      nca_body<false>(xv, Wb, maskv, mw, outv, smem);
}

// ---------------------------------------------------------------------------
extern "C" void kernel_launch(void* const* d_in, const int* in_sizes, int n_in,
                              void* d_out, int out_size, void* d_ws, size_t ws_size,
                              hipStream_t stream) {
  // d_in: 0=x, 1=w1, 2=b1, 3=w2, 4=b2, 5=w3, 6=b3, 7=update_mask
  u8* Wb = (u8*)d_ws + 64;

  prep_weights<<<(PREP_N + 255) / 256, 256, 0, stream>>>(
      d_in[1], d_in[2], d_in[3], d_in[4], d_in[5], d_in[6], Wb);

  const int pixels = in_sizes[7];            // B*H*W = 1048576
  const int blocks = pixels / 512;           // 2048: two 256-px rows per block
  nca_main<<<blocks, 256, 0, stream>>>(d_in[0], (const u16*)d_in[1], Wb,
                                       d_in[7], d_out);
}

// Round 8
// 187.375 us; speedup vs baseline: 1.2471x; 1.0107x over previous
//
#include <hip/hip_runtime.h>
#include <hip/hip_bf16.h>

typedef unsigned int u32;
typedef unsigned short u16;
typedef unsigned char u8;

typedef float f32x16 __attribute__((ext_vector_type(16)));
typedef short bf16x8 __attribute__((ext_vector_type(8)));

// ---- workspace layout (bytes after 64B header) -----------------------------
// A1eff[9 off][2 mt][2 hi][32 lane][8 k] bf16 (stencil folded into W1^T) 18432B
// A1b  [2 mt][2 hi][32 lane][8 k]       bf16 (b1/16 replicated)          2048B
// WT2p [32 ch][80 k]  bf16  K-PERMUTED to match o1 register order        5120B
// WT3p [32 row][32 k] bf16  K-permuted to o2 order, M-permuted so lane
//                           (n,hh) ends with ch 8hh..8hh+7 contiguous    2048B
// B3   [16] f32                                                            64B
#define OFF_A1  0
#define OFF_A1B 18432
#define OFF_WT2 20480
#define OFF_WT3 25600
#define OFF_B3  27648
#define PREP_N  13840   // 9216 + 1024 + 2560 + 1024 + 16

__device__ __forceinline__ float bf2f(u16 h) {
  return __uint_as_float(((u32)h) << 16);
}
__device__ __forceinline__ u16 f2bf(float f) {  // RNE (prep only)
  u32 u = __float_as_uint(f);
  return (u16)((u + 0x7FFFu + ((u >> 16) & 1u)) >> 16);
}
// hot-path pack: single v_cvt_pk_bf16_f32 (RNE; verified R7)
__device__ __forceinline__ u32 pkbf(float a, float b) {
  u32 r;
  asm("v_cvt_pk_bf16_f32 %0, %1, %2" : "=v"(r) : "v"(a), "v"(b));
  return r;  // lo16 = bf16(a), hi16 = bf16(b)
}
__device__ __forceinline__ float rdv(const void* s, int i, bool bf) {
  return bf ? bf2f(((const u16*)s)[i]) : ((const float*)s)[i];
}

// ---------------------------------------------------------------------------
// Weight prep (probe folded in; verified R1-R7).
// K-permutation (layers 2,3): logical k-slot = 16s + 8hh + 2q + e must hold
// the channel resident in o{1,2}[4s+q] bf16-half e of a hh-half lane:
//   L2: c = 32*(s>>1) + 8*(2*(s&1)+(q>>1)) + 4*hh + 2*(q&1) + e
//   L3: c = 8*(2*s+(q>>1)) + 4*hh + 2*(q&1) + e
// M-permutation (layer 3): row r<16 holds output channel
//   cout(r) = (r&3) + 4*((r>>3)&1) + 8*((r>>2)&1)   (rows 16..31 zero)
// so lane (n,hh) reg e (e<8) = channel 8hh+e  -> contiguous 32B per lane.
// ---------------------------------------------------------------------------
__global__ void prep_weights(const void* __restrict__ w1, const void* __restrict__ b1,
                             const void* __restrict__ w2, const void* __restrict__ b2,
                             const void* __restrict__ w3, const void* __restrict__ b3,
                             u8* __restrict__ Wb) {
  __shared__ int sg;
  if (threadIdx.x == 0) sg = 0;
  __syncthreads();
  {
    const u16* w1h = (const u16*)w1;
    int g = 0;
#pragma unroll
    for (int k = 0; k < 8; ++k) {
      u16 h = w1h[threadIdx.x * 8 + k];
      int e = (h >> 7) & 0xFF;
      if (e >= 0xC0) g++;
    }
    if (g) atomicAdd(&sg, g);
  }
  __syncthreads();
  const bool bf = (sg == 0);

  int i = blockIdx.x * 256 + threadIdx.x;
  if (i >= PREP_N) return;
  if (i < 9216) {                       // A1eff
    int off = i >> 10, rem = i & 1023;
    int mt = rem >> 9, hi = (rem >> 8) & 1, l = (rem >> 3) & 31, k8 = i & 7;
    int ch = mt * 32 + l, k = hi * 8 + k8;
    int oi = off / 3, oj = off % 3;
    const float axv[3] = {1.f, 2.f, 1.f};
    const float bxv[3] = {-1.f, 0.f, 1.f};
    float ci  = (oi == 1 && oj == 1) ? 1.f : 0.f;
    float dxv = axv[oi] * bxv[oj] * 0.125f;
    float dyv = axv[oj] * bxv[oi] * 0.125f;
    float v = ci  * rdv(w1, (3 * k + 0) * 64 + ch, bf)
            + dxv * rdv(w1, (3 * k + 1) * 64 + ch, bf)
            + dyv * rdv(w1, (3 * k + 2) * 64 + ch, bf);
    ((u16*)(Wb + OFF_A1))[i] = f2bf(v);
  } else if (i < 10240) {               // A1b: b1/16 in every k slot
    int j = i - 9216;
    int mt = j >> 9, l = (j >> 3) & 31;
    ((u16*)(Wb + OFF_A1B))[j] = f2bf(rdv(b1, mt * 32 + l, bf) * 0.0625f);
  } else if (i < 12800) {               // WT2p (K-permuted)
    int j = i - 10240, n = j / 80, k = j - n * 80;
    float v;
    if (k < 64) {
      int s = k >> 4, hh = (k >> 3) & 1, q = (k & 7) >> 1, e = k & 1;
      int c = 32 * (s >> 1) + 8 * (2 * (s & 1) + (q >> 1)) + 4 * hh + 2 * (q & 1) + e;
      v = rdv(w2, c * 32 + n, bf);
    } else {
      v = (k == 64) ? rdv(b2, n, bf) : 0.0f;
    }
    ((u16*)(Wb + OFF_WT2))[j] = f2bf(v);
  } else if (i < 13824) {               // WT3p (K- and M-permuted)
    int j = i - 12800, n = j >> 5, k = j & 31;
    float v = 0.0f;
    if (n < 16) {
      int cout = (n & 3) + 4 * ((n >> 3) & 1) + 8 * ((n >> 2) & 1);
      int s = k >> 4, hh = (k >> 3) & 1, q = (k & 7) >> 1, e = k & 1;
      int cin = 8 * (2 * s + (q >> 1)) + 4 * hh + 2 * (q & 1) + e;
      v = rdv(w3, cin * 16 + cout, bf);
    }
    ((u16*)(Wb + OFF_WT3))[j] = f2bf(v);
  } else {                              // B3 f32
    int j = i - 13824;
    ((float*)(Wb + OFF_B3))[j] = rdv(b3, j, bf);
  }
}

// ---------------------------------------------------------------------------
// Main kernel
// ---------------------------------------------------------------------------
// tanh(x) = 1 - 2/(e^{2x}+1);  e^{2x} = 2^{x * 2/ln2}  (verified R7)
__device__ __forceinline__ float fast_tanh(float x) {
  float e = __builtin_amdgcn_exp2f(x * 2.8853900817779268f);
  float r = __builtin_amdgcn_rcpf(e + 1.0f);
  return fmaf(-2.0f, r, 1.0f);
}

union U4 { uint4 q; u32 u[4]; bf16x8 h; float4 f; };

__device__ __forceinline__ void wave_lds_fence() {
  __builtin_amdgcn_wave_barrier();
  __asm__ __volatile__("s_waitcnt lgkmcnt(0)" ::: "memory");
  __builtin_amdgcn_wave_barrier();
}

#define MFMA(a, b, c) __builtin_amdgcn_mfma_f32_32x32x16_bf16((a), (b), (c), 0, 0, 0)

// LDS: xs[4 rows][258 cols][16 ch bf16] (stride 8256B, halo cols 0/257 zero)
//    + scratch[4 waves][32 px][80B]  (per-tile; verified R6).
// R6/R7: 43264B -> 3 blk/CU, FETCH 90MB, WRITE exact 64MiB.
// R8: WT2/WT3/bias fragments are TILE-INVARIANT but were re-gathered from L2
// every tile (lane-stride 160B/64B, ~300cyc latency, right behind the tanh
// chain with nothing to hide under). Hoisted to registers: +32 VGPR
// (~104+64acc=168 <= 170 @ 3 waves/SIMD). Spill tripwire: WRITE_SIZE.
#define XS_STRIDE 8256
#define SCR_OFF   33024
#define SCR_WAVE  2560
#define LDS_TOTAL 43264

template <bool BF16>
__device__ __forceinline__ void nca_body(const void* __restrict__ xv,
                                         const u8* __restrict__ Wb,
                                         const void* __restrict__ maskv, int mw,
                                         void* __restrict__ outv,
                                         u8* __restrict__ xs) {
  const int tid = threadIdx.x;
  const int l   = tid & 63;
  const int wid = tid >> 6;
  const int l31 = l & 31;
  const int hi  = l >> 5;
  const int img   = blockIdx.x >> 7;
  const int r0    = (blockIdx.x & 127) << 1;      // first of 2 output rows

  // ---- stage x rows r0-1 .. r0+2 into LDS as bf16 (zero halo) -------------
  if (tid < 8) {        // halo cols 0 and 257, 4 rows
    int rr = tid >> 1, side = tid & 1;
    uint4 z = make_uint4(0, 0, 0, 0);
    uint4* d = (uint4*)(xs + rr * XS_STRIDE + (side ? 257 : 0) * 32);
    d[0] = z; d[1] = z;
  }
#pragma unroll
  for (int rr = 0; rr < 4; ++rr) {
    int hr = r0 - 1 + rr;
    bool valid = (hr >= 0) && (hr <= 255);
    if (BF16) {
      const u16* src = (const u16*)xv + ((size_t)(img * 256 + hr) << 12);
#pragma unroll
      for (int s = 0; s < 2; ++s) {
        int c = s * 256 + tid;        // 16B chunk: col c>>1, half c&1
        uint4 v = make_uint4(0, 0, 0, 0);
        if (valid) v = *(const uint4*)(src + c * 8);
        *(uint4*)(xs + rr * XS_STRIDE + ((c >> 1) + 1) * 32 + (c & 1) * 16) = v;
      }
    } else {
      const float* src = (const float*)xv + ((size_t)(img * 256 + hr) << 12);
#pragma unroll
      for (int k = 0; k < 4; ++k) {
        int q = k * 256 + tid;        // float4 #q: col q>>2, ch-quad q&3
        uint2 w = make_uint2(0, 0);
        if (valid) {
          float4 v = *(const float4*)(src + q * 4);
          w.x = pkbf(v.x, v.y); w.y = pkbf(v.z, v.w);
        }
        *(uint2*)(xs + rr * XS_STRIDE + ((q >> 2) + 1) * 32 + (q & 3) * 8) = w;
      }
    }
  }
  __syncthreads();

  const int sr      = wid >> 1;                 // wave's top staged row
  const int colbase = (wid & 1) * 128;          // wave's column half
  const int gr      = img * 256 + r0 + sr;      // global image row
  const int growpix = gr << 8;                  // pixel index of row start

  // ---- hoisted invariants -------------------------------------------------
  bf16x8 A1b[2];
#pragma unroll
  for (int mt = 0; mt < 2; ++mt) {
    U4 t; t.q = *(const uint4*)(Wb + OFF_A1B + ((mt * 2 + hi) * 32 + l31) * 16);
    A1b[mt] = t.h;
  }
  U4 ones; ones.u[0] = ones.u[1] = ones.u[2] = ones.u[3] = 0x3F803F80u;
  const float* B3f = (const float*)(Wb + OFF_B3);
  float4 b3lo = *(const float4*)(B3f + 8 * hi);       // ch 8hi+0..3
  float4 b3hi4 = *(const float4*)(B3f + 8 * hi + 4);  // ch 8hi+4..7
  u8* scr = xs + SCR_OFF + wid * SCR_WAVE;

  // R8: tile-invariant layer-2/3 weight fragments -> registers (were
  // re-gathered from L2 every tile; 160B/64B lane strides, ~300cyc exposed)
  bf16x8 A2h[5], A3h[2];
#pragma unroll
  for (int s = 0; s < 5; ++s) {
    U4 t; t.q = *(const uint4*)(Wb + OFF_WT2 + l31 * 160 + s * 32 + hi * 16);
    A2h[s] = t.h;
  }
#pragma unroll
  for (int s = 0; s < 2; ++s) {
    U4 t; t.q = *(const uint4*)(Wb + OFF_WT3 + l31 * 64 + s * 32 + hi * 16);
    A3h[s] = t.h;
  }
  U4 bbf; bbf.u[0] = hi ? 0u : 0x00003F80u; bbf.u[1] = 0; bbf.u[2] = 0; bbf.u[3] = 0;

  // ---- 4 tiles of 32 px each ----------------------------------------------
#pragma unroll
  for (int t = 0; t < 4; ++t) {
    const int cb = colbase + t * 32;

    // ---- layer 1: 2 bias MFMA + 9 shifted-offset MFMAs per M-tile ---------
    f32x16 c0 = {0,0,0,0,0,0,0,0,0,0,0,0,0,0,0,0};
    f32x16 c1 = {0,0,0,0,0,0,0,0,0,0,0,0,0,0,0,0};
    c0 = MFMA(A1b[0], ones.h, c0);
    c1 = MFMA(A1b[1], ones.h, c1);
#pragma unroll
    for (int off = 0; off < 9; ++off) {
      const int oi = off / 3, oj = off % 3;
      U4 bx; bx.q = *(const uint4*)(xs + (sr + oi) * XS_STRIDE +
                                    (cb + l31 + oj) * 32 + hi * 16);
      U4 a0; a0.q = *(const uint4*)(Wb + OFF_A1 + (((off * 2 + 0) * 2 + hi) * 32 + l31) * 16);
      U4 a1; a1.q = *(const uint4*)(Wb + OFF_A1 + (((off * 2 + 1) * 2 + hi) * 32 + l31) * 16);
      c0 = MFMA(a0.h, bx.h, c0);
      c1 = MFMA(a1.h, bx.h, c1);
    }

    // tanh + pack: o1[mt*8+g*2+pp] = ch(32mt+8g+4hi+2pp, +1)
    u32 o1[16];
#pragma unroll
    for (int g = 0; g < 4; ++g)
#pragma unroll
      for (int pp = 0; pp < 2; ++pp) {
        o1[g * 2 + pp]     = pkbf(fast_tanh(c0[g * 4 + 2 * pp]), fast_tanh(c0[g * 4 + 2 * pp + 1]));
        o1[8 + g * 2 + pp] = pkbf(fast_tanh(c1[g * 4 + 2 * pp]), fast_tanh(c1[g * 4 + 2 * pp + 1]));
      }

    // ---- layer 2: B-frag = o1[4s..4s+3] (hoisted K-permuted weights) ------
    f32x16 c2 = {0,0,0,0,0,0,0,0,0,0,0,0,0,0,0,0};
#pragma unroll
    for (int s = 0; s < 4; ++s) {
      U4 bfr; bfr.u[0] = o1[4*s]; bfr.u[1] = o1[4*s+1]; bfr.u[2] = o1[4*s+2]; bfr.u[3] = o1[4*s+3];
      c2 = MFMA(A2h[s], bfr.h, c2);
    }
    c2 = MFMA(A2h[4], bbf.h, c2);
    u32 o2[8];
#pragma unroll
    for (int g = 0; g < 4; ++g)
#pragma unroll
      for (int pp = 0; pp < 2; ++pp)
        o2[g * 2 + pp] = pkbf(fast_tanh(c2[g * 4 + 2 * pp]), fast_tanh(c2[g * 4 + 2 * pp + 1]));

    // ---- layer 3: B-frag = o2[4s..4s+3]; hoisted M-permuted weights -------
    f32x16 c3 = {0,0,0,0,0,0,0,0,0,0,0,0,0,0,0,0};
#pragma unroll
    for (int s = 0; s < 2; ++s) {
      U4 bfr; bfr.u[0] = o2[4*s]; bfr.u[1] = o2[4*s+1]; bfr.u[2] = o2[4*s+2]; bfr.u[3] = o2[4*s+3];
      c3 = MFMA(A3h[s], bfr.h, c3);
    }

    // dx + b3 -> per-wave LDS scratch (transpose for coalesced epilogue)
    U4 w0, w1;
    w0.f.x = c3[0] + b3lo.x;  w0.f.y = c3[1] + b3lo.y;
    w0.f.z = c3[2] + b3lo.z;  w0.f.w = c3[3] + b3lo.w;
    w1.f.x = c3[4] + b3hi4.x; w1.f.y = c3[5] + b3hi4.y;
    w1.f.z = c3[6] + b3hi4.z; w1.f.w = c3[7] + b3hi4.w;
    u8* sa = scr + l31 * 80 + hi * 32;
    *(float4*)(sa) = w0.f;
    *(float4*)(sa + 16) = w1.f;
    wave_lds_fence();

    // ---- epilogue for this tile's 32 px: coalesced x reads + out writes ---
#pragma unroll
    for (int P = 0; P < 2; ++P) {
      const int px_l = P * 16 + (l >> 2);       // 0..31
      const int qd   = l & 3;                   // channel quad
      float4 dx = *(const float4*)(scr + px_l * 80 + qd * 16);
      const int gpx = growpix + cb + px_l;
      bool ms;
      if (mw == 1)      ms = ((const u8*)maskv)[gpx] != 0;
      else if (mw == 2) ms = ((const u16*)maskv)[gpx] != 0;
      else              ms = ((const u32*)maskv)[gpx] != 0;
      const float mf = ms ? 1.0f : 0.0f;
      const int e = gpx * 16 + qd * 4;
      if (BF16) {
        uint2 xu = *(const uint2*)((const u16*)xv + e);
        float x0 = bf2f((u16)(xu.x & 0xFFFF)), x1 = bf2f((u16)(xu.x >> 16));
        float x2 = bf2f((u16)(xu.y & 0xFFFF)), x3 = bf2f((u16)(xu.y >> 16));
        float o0 = fmaf(dx.x, mf, x0), o1v = fmaf(dx.y, mf, x1);
        float o2v = fmaf(dx.z, mf, x2), o3v = fmaf(dx.w, mf, x3);
        uint2 w; w.x = pkbf(o0, o1v); w.y = pkbf(o2v, o3v);
        *(uint2*)((u16*)outv + e) = w;
      } else {
        float4 xc = *(const float4*)((const float*)xv + e);
        float4 o;
        o.x = fmaf(dx.x, mf, xc.x); o.y = fmaf(dx.y, mf, xc.y);
        o.z = fmaf(dx.z, mf, xc.z); o.w = fmaf(dx.w, mf, xc.w);
        *(float4*)((float*)outv + e) = o;
      }
    }
    wave_lds_fence();   // reads done before next tile's scratch writes
  }
}

__global__ __launch_bounds__(256, 3) void nca_main(const void* __restrict__ xv,
                                                   const u16* __restrict__ w1h,
                                                   const u8* __restrict__ Wb,
                                                   const void* __restrict__ maskv,
                                                   void* __restrict__ outv) {
  __shared__ __align__(16) u8 smem[LDS_TOTAL];
  __shared__ int sg, su8, sbf;
  if (threadIdx.x == 0) { sg = 0; su8 = 0; sbf = 0; }
  __syncthreads();
  {  // in-block probe (verified R1-R7; L2-hot reads, ~no cost)
    int g = 0;
#pragma unroll
    for (int k = 0; k < 8; ++k) {
      u16 h = w1h[threadIdx.x * 8 + k];
      int e = (h >> 7) & 0xFF;
      if (e >= 0xC0) g++;
    }
    if (g) atomicAdd(&sg, g);
    u32 w = ((const u32*)maskv)[threadIdx.x];
    bool bytes01 = ((w & 0xFEFEFEFEu) == 0u);
    int bsum = (int)(w & 1u) + (int)((w >> 8) & 1u) +
               (int)((w >> 16) & 1u) + (int)((w >> 24) & 1u);
    if (bytes01 && bsum >= 2) atomicAdd(&su8, 1);
    if (w == 0x3F803F80u || w == 0x00003F80u) atomicAdd(&sbf, 1);
  }
  __syncthreads();
  const bool isbf = (sg == 0);                  // wave-uniform
  const int mw = (su8 > 0) ? 1 : ((sbf > 0) ? 2 : 4);

  // NO XCD swizzle (neutral-at-best per R1/R3 traffic accounting).
  if (isbf) nca_body<true>(xv, Wb, maskv, mw, outv, smem);
  else      nca_body<false>(xv, Wb, maskv, mw, outv, smem);
}

// ---------------------------------------------------------------------------
extern "C" void kernel_launch(void* const* d_in, const int* in_sizes, int n_in,
                              void* d_out, int out_size, void* d_ws, size_t ws_size,
                              hipStream_t stream) {
  // d_in: 0=x, 1=w1, 2=b1, 3=w2, 4=b2, 5=w3, 6=b3, 7=update_mask
  u8* Wb = (u8*)d_ws + 64;

  prep_weights<<<(PREP_N + 255) / 256, 256, 0, stream>>>(
      d_in[1], d_in[2], d_in[3], d_in[4], d_in[5], d_in[6], Wb);

  const int pixels = in_sizes[7];            // B*H*W = 1048576
  const int blocks = pixels / 512;           // 2048: two 256-px rows per block
  nca_main<<<blocks, 256, 0, stream>>>(d_in[0], (const u16*)d_in[1], Wb,
                                       d_in[7], d_out);
}

// Round 9
// 177.477 us; speedup vs baseline: 1.3166x; 1.0558x over previous
//
#include <hip/hip_runtime.h>
#include <hip/hip_bf16.h>

typedef unsigned int u32;
typedef unsigned short u16;
typedef unsigned char u8;

typedef float f32x16 __attribute__((ext_vector_type(16)));
typedef short bf16x8 __attribute__((ext_vector_type(8)));

// ---- workspace layout (bytes after 64B header) -----------------------------
// A1eff[9 off][2 mt][2 hi][32 lane][8 k] bf16 (stencil folded into W1^T) 18432B
// A1b  [2 mt][2 hi][32 lane][8 k]       bf16 (b1/16 replicated)          2048B
// WT2p [32 ch][80 k]  bf16  K-PERMUTED to match o1 register order        5120B
// WT3p [32 row][32 k] bf16  K-permuted to o2 order, M-permuted so lane
//                           (n,hh) ends with ch 8hh..8hh+7 contiguous    2048B
// B3   [16] f32                                                            64B
#define OFF_A1  0
#define OFF_A1B 18432
#define OFF_WT2 20480
#define OFF_WT3 25600
#define OFF_B3  27648
#define PREP_N  13840   // 9216 + 1024 + 2560 + 1024 + 16

__device__ __forceinline__ float bf2f(u16 h) {
  return __uint_as_float(((u32)h) << 16);
}
__device__ __forceinline__ u16 f2bf(float f) {  // RNE (prep only)
  u32 u = __float_as_uint(f);
  return (u16)((u + 0x7FFFu + ((u >> 16) & 1u)) >> 16);
}
// hot-path pack: single v_cvt_pk_bf16_f32 (RNE; verified R7)
__device__ __forceinline__ u32 pkbf(float a, float b) {
  u32 r;
  asm("v_cvt_pk_bf16_f32 %0, %1, %2" : "=v"(r) : "v"(a), "v"(b));
  return r;  // lo16 = bf16(a), hi16 = bf16(b)
}
__device__ __forceinline__ float rdv(const void* s, int i, bool bf) {
  return bf ? bf2f(((const u16*)s)[i]) : ((const float*)s)[i];
}

// ---------------------------------------------------------------------------
// Weight prep (probe folded in; verified R1-R8).
// K-permutation (layers 2,3): logical k-slot = 16s + 8hh + 2q + e must hold
// the channel resident in o{1,2}[4s+q] bf16-half e of a hh-half lane:
//   L2: c = 32*(s>>1) + 8*(2*(s&1)+(q>>1)) + 4*hh + 2*(q&1) + e
//   L3: c = 8*(2*s+(q>>1)) + 4*hh + 2*(q&1) + e
// M-permutation (layer 3): row r<16 holds output channel
//   cout(r) = (r&3) + 4*((r>>3)&1) + 8*((r>>2)&1)   (rows 16..31 zero)
// so lane (n,hh) reg e (e<8) = channel 8hh+e  -> contiguous 32B per lane.
// ---------------------------------------------------------------------------
__global__ void prep_weights(const void* __restrict__ w1, const void* __restrict__ b1,
                             const void* __restrict__ w2, const void* __restrict__ b2,
                             const void* __restrict__ w3, const void* __restrict__ b3,
                             u8* __restrict__ Wb) {
  __shared__ int sg;
  if (threadIdx.x == 0) sg = 0;
  __syncthreads();
  {
    const u16* w1h = (const u16*)w1;
    int g = 0;
#pragma unroll
    for (int k = 0; k < 8; ++k) {
      u16 h = w1h[threadIdx.x * 8 + k];
      int e = (h >> 7) & 0xFF;
      if (e >= 0xC0) g++;
    }
    if (g) atomicAdd(&sg, g);
  }
  __syncthreads();
  const bool bf = (sg == 0);

  int i = blockIdx.x * 256 + threadIdx.x;
  if (i >= PREP_N) return;
  if (i < 9216) {                       // A1eff
    int off = i >> 10, rem = i & 1023;
    int mt = rem >> 9, hi = (rem >> 8) & 1, l = (rem >> 3) & 31, k8 = i & 7;
    int ch = mt * 32 + l, k = hi * 8 + k8;
    int oi = off / 3, oj = off % 3;
    const float axv[3] = {1.f, 2.f, 1.f};
    const float bxv[3] = {-1.f, 0.f, 1.f};
    float ci  = (oi == 1 && oj == 1) ? 1.f : 0.f;
    float dxv = axv[oi] * bxv[oj] * 0.125f;
    float dyv = axv[oj] * bxv[oi] * 0.125f;
    float v = ci  * rdv(w1, (3 * k + 0) * 64 + ch, bf)
            + dxv * rdv(w1, (3 * k + 1) * 64 + ch, bf)
            + dyv * rdv(w1, (3 * k + 2) * 64 + ch, bf);
    ((u16*)(Wb + OFF_A1))[i] = f2bf(v);
  } else if (i < 10240) {               // A1b: b1/16 in every k slot
    int j = i - 9216;
    int mt = j >> 9, l = (j >> 3) & 31;
    ((u16*)(Wb + OFF_A1B))[j] = f2bf(rdv(b1, mt * 32 + l, bf) * 0.0625f);
  } else if (i < 12800) {               // WT2p (K-permuted)
    int j = i - 10240, n = j / 80, k = j - n * 80;
    float v;
    if (k < 64) {
      int s = k >> 4, hh = (k >> 3) & 1, q = (k & 7) >> 1, e = k & 1;
      int c = 32 * (s >> 1) + 8 * (2 * (s & 1) + (q >> 1)) + 4 * hh + 2 * (q & 1) + e;
      v = rdv(w2, c * 32 + n, bf);
    } else {
      v = (k == 64) ? rdv(b2, n, bf) : 0.0f;
    }
    ((u16*)(Wb + OFF_WT2))[j] = f2bf(v);
  } else if (i < 13824) {               // WT3p (K- and M-permuted)
    int j = i - 12800, n = j >> 5, k = j & 31;
    float v = 0.0f;
    if (n < 16) {
      int cout = (n & 3) + 4 * ((n >> 3) & 1) + 8 * ((n >> 2) & 1);
      int s = k >> 4, hh = (k >> 3) & 1, q = (k & 7) >> 1, e = k & 1;
      int cin = 8 * (2 * s + (q >> 1)) + 4 * hh + 2 * (q & 1) + e;
      v = rdv(w3, cin * 16 + cout, bf);
    }
    ((u16*)(Wb + OFF_WT3))[j] = f2bf(v);
  } else {                              // B3 f32
    int j = i - 13824;
    ((float*)(Wb + OFF_B3))[j] = rdv(b3, j, bf);
  }
}

// ---------------------------------------------------------------------------
// Main kernel
// ---------------------------------------------------------------------------
// tanh(x) = 1 - 2/(e^{2x}+1);  e^{2x} = 2^{x * 2/ln2}  (verified R7)
__device__ __forceinline__ float fast_tanh(float x) {
  float e = __builtin_amdgcn_exp2f(x * 2.8853900817779268f);
  float r = __builtin_amdgcn_rcpf(e + 1.0f);
  return fmaf(-2.0f, r, 1.0f);
}

union U4 { uint4 q; u32 u[4]; bf16x8 h; float4 f; };

__device__ __forceinline__ void wave_lds_fence() {
  __builtin_amdgcn_wave_barrier();
  __asm__ __volatile__("s_waitcnt lgkmcnt(0)" ::: "memory");
  __builtin_amdgcn_wave_barrier();
}

#define MFMA(a, b, c) __builtin_amdgcn_mfma_f32_32x32x16_bf16((a), (b), (c), 0, 0, 0)

// LDS: xs[4 rows][258 cols][16 ch bf16] (stride 8256B, halo cols 0/257 zero)
//    + scratch[4 waves][32 px][80B]  (per-tile; verified R6).
// R6-R8: 43264B -> 3 blk/CU, FETCH ~90MB, WRITE exact 64MiB; 4 blk/CU is
// traffic-poisoned (R1/R3/R5) — occupancy closed. Remaining gap is exposed
// memory latency at 3 waves/SIMD (43% issue-slot use, no pipe saturated).
// R9: per-tile PREFETCH of the epilogue x+mask into registers at tile start
// (~2500 cycles of MFMA/tanh cover them; R2's version of this hoisted ALL
// tiles and spilled — per-tile is ~12 live VGPRs, ledger 88+64=152<170).
#define XS_STRIDE 8256
#define SCR_OFF   33024
#define SCR_WAVE  2560
#define LDS_TOTAL 43264

template <bool BF16>
__device__ __forceinline__ void nca_body(const void* __restrict__ xv,
                                         const u8* __restrict__ Wb,
                                         const void* __restrict__ maskv, int mw,
                                         void* __restrict__ outv,
                                         u8* __restrict__ xs) {
  const int tid = threadIdx.x;
  const int l   = tid & 63;
  const int wid = tid >> 6;
  const int l31 = l & 31;
  const int hi  = l >> 5;
  const int img   = blockIdx.x >> 7;
  const int r0    = (blockIdx.x & 127) << 1;      // first of 2 output rows

  // ---- stage x rows r0-1 .. r0+2 into LDS as bf16 (zero halo) -------------
  if (tid < 8) {        // halo cols 0 and 257, 4 rows
    int rr = tid >> 1, side = tid & 1;
    uint4 z = make_uint4(0, 0, 0, 0);
    uint4* d = (uint4*)(xs + rr * XS_STRIDE + (side ? 257 : 0) * 32);
    d[0] = z; d[1] = z;
  }
#pragma unroll
  for (int rr = 0; rr < 4; ++rr) {
    int hr = r0 - 1 + rr;
    bool valid = (hr >= 0) && (hr <= 255);
    if (BF16) {
      const u16* src = (const u16*)xv + ((size_t)(img * 256 + hr) << 12);
#pragma unroll
      for (int s = 0; s < 2; ++s) {
        int c = s * 256 + tid;        // 16B chunk: col c>>1, half c&1
        uint4 v = make_uint4(0, 0, 0, 0);
        if (valid) v = *(const uint4*)(src + c * 8);
        *(uint4*)(xs + rr * XS_STRIDE + ((c >> 1) + 1) * 32 + (c & 1) * 16) = v;
      }
    } else {
      const float* src = (const float*)xv + ((size_t)(img * 256 + hr) << 12);
#pragma unroll
      for (int k = 0; k < 4; ++k) {
        int q = k * 256 + tid;        // float4 #q: col q>>2, ch-quad q&3
        uint2 w = make_uint2(0, 0);
        if (valid) {
          float4 v = *(const float4*)(src + q * 4);
          w.x = pkbf(v.x, v.y); w.y = pkbf(v.z, v.w);
        }
        *(uint2*)(xs + rr * XS_STRIDE + ((q >> 2) + 1) * 32 + (q & 3) * 8) = w;
      }
    }
  }
  __syncthreads();

  const int sr      = wid >> 1;                 // wave's top staged row
  const int colbase = (wid & 1) * 128;          // wave's column half
  const int gr      = img * 256 + r0 + sr;      // global image row
  const int growpix = gr << 8;                  // pixel index of row start

  // ---- hoisted invariants -------------------------------------------------
  bf16x8 A1b[2];
#pragma unroll
  for (int mt = 0; mt < 2; ++mt) {
    U4 t; t.q = *(const uint4*)(Wb + OFF_A1B + ((mt * 2 + hi) * 32 + l31) * 16);
    A1b[mt] = t.h;
  }
  U4 ones; ones.u[0] = ones.u[1] = ones.u[2] = ones.u[3] = 0x3F803F80u;
  const float* B3f = (const float*)(Wb + OFF_B3);
  float4 b3lo = *(const float4*)(B3f + 8 * hi);       // ch 8hi+0..3
  float4 b3hi4 = *(const float4*)(B3f + 8 * hi + 4);  // ch 8hi+4..7
  u8* scr = xs + SCR_OFF + wid * SCR_WAVE;

  // tile-invariant layer-2/3 weight fragments in registers (verified R8)
  bf16x8 A2h[5], A3h[2];
#pragma unroll
  for (int s = 0; s < 5; ++s) {
    U4 t; t.q = *(const uint4*)(Wb + OFF_WT2 + l31 * 160 + s * 32 + hi * 16);
    A2h[s] = t.h;
  }
#pragma unroll
  for (int s = 0; s < 2; ++s) {
    U4 t; t.q = *(const uint4*)(Wb + OFF_WT3 + l31 * 64 + s * 32 + hi * 16);
    A3h[s] = t.h;
  }
  U4 bbf; bbf.u[0] = hi ? 0u : 0x00003F80u; bbf.u[1] = 0; bbf.u[2] = 0; bbf.u[3] = 0;

  // epilogue lane geometry (tile-invariant parts)
  const int ep_px = l >> 2;                     // 0..15 (P adds 16)
  const int ep_qd = l & 3;                      // channel quad

  // ---- 4 tiles of 32 px each ----------------------------------------------
#pragma unroll
  for (int t = 0; t < 4; ++t) {
    const int cb = colbase + t * 32;

    // ---- R9: prefetch epilogue x + mask for THIS tile (issued here, ------
    // consumed after the fence; MFMA/tanh below cover the ~300cyc latency)
    const int gpx1 = growpix + cb + ep_px;        // P=0 pixel
    const int gpx2 = gpx1 + 16;                   // P=1 pixel
    const int e1 = gpx1 * 16 + ep_qd * 4;
    const int e2 = gpx2 * 16 + ep_qd * 4;
    bool ms1, ms2;
    if (mw == 1)      { ms1 = ((const u8*)maskv)[gpx1] != 0;  ms2 = ((const u8*)maskv)[gpx2] != 0; }
    else if (mw == 2) { ms1 = ((const u16*)maskv)[gpx1] != 0; ms2 = ((const u16*)maskv)[gpx2] != 0; }
    else              { ms1 = ((const u32*)maskv)[gpx1] != 0; ms2 = ((const u32*)maskv)[gpx2] != 0; }
    const float mf1 = ms1 ? 1.0f : 0.0f;
    const float mf2 = ms2 ? 1.0f : 0.0f;
    uint2 xu1, xu2;           // BF16 path payload
    float4 xc1, xc2;          // f32 path payload
    if (BF16) {
      xu1 = *(const uint2*)((const u16*)xv + e1);
      xu2 = *(const uint2*)((const u16*)xv + e2);
    } else {
      xc1 = *(const float4*)((const float*)xv + e1);
      xc2 = *(const float4*)((const float*)xv + e2);
    }

    // ---- layer 1: 2 bias MFMA + 9 shifted-offset MFMAs per M-tile ---------
    f32x16 c0 = {0,0,0,0,0,0,0,0,0,0,0,0,0,0,0,0};
    f32x16 c1 = {0,0,0,0,0,0,0,0,0,0,0,0,0,0,0,0};
    c0 = MFMA(A1b[0], ones.h, c0);
    c1 = MFMA(A1b[1], ones.h, c1);
#pragma unroll
    for (int off = 0; off < 9; ++off) {
      const int oi = off / 3, oj = off % 3;
      U4 bx; bx.q = *(const uint4*)(xs + (sr + oi) * XS_STRIDE +
                                    (cb + l31 + oj) * 32 + hi * 16);
      U4 a0; a0.q = *(const uint4*)(Wb + OFF_A1 + (((off * 2 + 0) * 2 + hi) * 32 + l31) * 16);
      U4 a1; a1.q = *(const uint4*)(Wb + OFF_A1 + (((off * 2 + 1) * 2 + hi) * 32 + l31) * 16);
      c0 = MFMA(a0.h, bx.h, c0);
      c1 = MFMA(a1.h, bx.h, c1);
    }

    // tanh + pack: o1[mt*8+g*2+pp] = ch(32mt+8g+4hi+2pp, +1)
    u32 o1[16];
#pragma unroll
    for (int g = 0; g < 4; ++g)
#pragma unroll
      for (int pp = 0; pp < 2; ++pp) {
        o1[g * 2 + pp]     = pkbf(fast_tanh(c0[g * 4 + 2 * pp]), fast_tanh(c0[g * 4 + 2 * pp + 1]));
        o1[8 + g * 2 + pp] = pkbf(fast_tanh(c1[g * 4 + 2 * pp]), fast_tanh(c1[g * 4 + 2 * pp + 1]));
      }

    // ---- layer 2: B-frag = o1[4s..4s+3] (hoisted K-permuted weights) ------
    f32x16 c2 = {0,0,0,0,0,0,0,0,0,0,0,0,0,0,0,0};
#pragma unroll
    for (int s = 0; s < 4; ++s) {
      U4 bfr; bfr.u[0] = o1[4*s]; bfr.u[1] = o1[4*s+1]; bfr.u[2] = o1[4*s+2]; bfr.u[3] = o1[4*s+3];
      c2 = MFMA(A2h[s], bfr.h, c2);
    }
    c2 = MFMA(A2h[4], bbf.h, c2);
    u32 o2[8];
#pragma unroll
    for (int g = 0; g < 4; ++g)
#pragma unroll
      for (int pp = 0; pp < 2; ++pp)
        o2[g * 2 + pp] = pkbf(fast_tanh(c2[g * 4 + 2 * pp]), fast_tanh(c2[g * 4 + 2 * pp + 1]));

    // ---- layer 3: B-frag = o2[4s..4s+3]; hoisted M-permuted weights -------
    f32x16 c3 = {0,0,0,0,0,0,0,0,0,0,0,0,0,0,0,0};
#pragma unroll
    for (int s = 0; s < 2; ++s) {
      U4 bfr; bfr.u[0] = o2[4*s]; bfr.u[1] = o2[4*s+1]; bfr.u[2] = o2[4*s+2]; bfr.u[3] = o2[4*s+3];
      c3 = MFMA(A3h[s], bfr.h, c3);
    }

    // dx + b3 -> per-wave LDS scratch (transpose for coalesced epilogue)
    U4 w0, w1;
    w0.f.x = c3[0] + b3lo.x;  w0.f.y = c3[1] + b3lo.y;
    w0.f.z = c3[2] + b3lo.z;  w0.f.w = c3[3] + b3lo.w;
    w1.f.x = c3[4] + b3hi4.x; w1.f.y = c3[5] + b3hi4.y;
    w1.f.z = c3[6] + b3hi4.z; w1.f.w = c3[7] + b3hi4.w;
    u8* sa = scr + l31 * 80 + hi * 32;
    *(float4*)(sa) = w0.f;
    *(float4*)(sa + 16) = w1.f;
    wave_lds_fence();

    // ---- epilogue: LDS dx + prefetched x/mask -> full-line stores ---------
    {
      float4 dx1 = *(const float4*)(scr + ep_px * 80 + ep_qd * 16);
      float4 dx2 = *(const float4*)(scr + (16 + ep_px) * 80 + ep_qd * 16);
      if (BF16) {
        float x10 = bf2f((u16)(xu1.x & 0xFFFF)), x11 = bf2f((u16)(xu1.x >> 16));
        float x12 = bf2f((u16)(xu1.y & 0xFFFF)), x13 = bf2f((u16)(xu1.y >> 16));
        float x20 = bf2f((u16)(xu2.x & 0xFFFF)), x21 = bf2f((u16)(xu2.x >> 16));
        float x22 = bf2f((u16)(xu2.y & 0xFFFF)), x23 = bf2f((u16)(xu2.y >> 16));
        uint2 wa, wb;
        wa.x = pkbf(fmaf(dx1.x, mf1, x10), fmaf(dx1.y, mf1, x11));
        wa.y = pkbf(fmaf(dx1.z, mf1, x12), fmaf(dx1.w, mf1, x13));
        wb.x = pkbf(fmaf(dx2.x, mf2, x20), fmaf(dx2.y, mf2, x21));
        wb.y = pkbf(fmaf(dx2.z, mf2, x22), fmaf(dx2.w, mf2, x23));
        *(uint2*)((u16*)outv + e1) = wa;
        *(uint2*)((u16*)outv + e2) = wb;
      } else {
        float4 oa, ob;
        oa.x = fmaf(dx1.x, mf1, xc1.x); oa.y = fmaf(dx1.y, mf1, xc1.y);
        oa.z = fmaf(dx1.z, mf1, xc1.z); oa.w = fmaf(dx1.w, mf1, xc1.w);
        ob.x = fmaf(dx2.x, mf2, xc2.x); ob.y = fmaf(dx2.y, mf2, xc2.y);
        ob.z = fmaf(dx2.z, mf2, xc2.z); ob.w = fmaf(dx2.w, mf2, xc2.w);
        *(float4*)((float*)outv + e1) = oa;
        *(float4*)((float*)outv + e2) = ob;
      }
    }
    wave_lds_fence();   // reads done before next tile's scratch writes
  }
}

__global__ __launch_bounds__(256, 3) void nca_main(const void* __restrict__ xv,
                                                   const u16* __restrict__ w1h,
                                                   const u8* __restrict__ Wb,
                                                   const void* __restrict__ maskv,
                                                   void* __restrict__ outv) {
  __shared__ __align__(16) u8 smem[LDS_TOTAL];
  __shared__ int sg, su8, sbf;
  if (threadIdx.x == 0) { sg = 0; su8 = 0; sbf = 0; }
  __syncthreads();
  {  // in-block probe (verified R1-R8; L2-hot reads, ~no cost)
    int g = 0;
#pragma unroll
    for (int k = 0; k < 8; ++k) {
      u16 h = w1h[threadIdx.x * 8 + k];
      int e = (h >> 7) & 0xFF;
      if (e >= 0xC0) g++;
    }
    if (g) atomicAdd(&sg, g);
    u32 w = ((const u32*)maskv)[threadIdx.x];
    bool bytes01 = ((w & 0xFEFEFEFEu) == 0u);
    int bsum = (int)(w & 1u) + (int)((w >> 8) & 1u) +
               (int)((w >> 16) & 1u) + (int)((w >> 24) & 1u);
    if (bytes01 && bsum >= 2) atomicAdd(&su8, 1);
    if (w == 0x3F803F80u || w == 0x00003F80u) atomicAdd(&sbf, 1);
  }
  __syncthreads();
  const bool isbf = (sg == 0);                  // wave-uniform
  const int mw = (su8 > 0) ? 1 : ((sbf > 0) ? 2 : 4);

  // NO XCD swizzle (neutral-at-best per R1/R3 traffic accounting).
  if (isbf) nca_body<true>(xv, Wb, maskv, mw, outv, smem);
  else      nca_body<false>(xv, Wb, maskv, mw, outv, smem);
}

// ---------------------------------------------------------------------------
extern "C" void kernel_launch(void* const* d_in, const int* in_sizes, int n_in,
                              void* d_out, int out_size, void* d_ws, size_t ws_size,
                              hipStream_t stream) {
  // d_in: 0=x, 1=w1, 2=b1, 3=w2, 4=b2, 5=w3, 6=b3, 7=update_mask
  u8* Wb = (u8*)d_ws + 64;

  prep_weights<<<(PREP_N + 255) / 256, 256, 0, stream>>>(
      d_in[1], d_in[2], d_in[3], d_in[4], d_in[5], d_in[6], Wb);

  const int pixels = in_sizes[7];            // B*H*W = 1048576
  const int blocks = pixels / 512;           // 2048: two 256-px rows per block
  nca_main<<<blocks, 256, 0, stream>>>(d_in[0], (const u16*)d_in[1], Wb,
                                       d_in[7], d_out);
}